// Round 1
// baseline (575.078 us; speedup 1.0000x reference)
//
#include <hip/hip_runtime.h>

typedef unsigned short ushort;
typedef __attribute__((ext_vector_type(8))) short short8;
typedef __attribute__((ext_vector_type(8))) unsigned short ushort8;
typedef __attribute__((ext_vector_type(4))) unsigned short ushort4v;
typedef __attribute__((ext_vector_type(4))) float fx4;

#define NB 32
#define CIN_ 512
#define NSP 256
#define COUT_ 2048
#define HEADS_ 8
#define DH 256
#define MAXNNZ (256*7)

__device__ __forceinline__ ushort f2bf(float f) {
    union { float f; unsigned u; } v; v.f = f;
    unsigned r = v.u + 0x7fffu + ((v.u >> 16) & 1u);
    return (ushort)(r >> 16);
}

// ---------------- top-7 per row of coeff (rows 0..255), emit COO for cols<256 -----
__global__ __launch_bounds__(256)
void topk_kernel(const float* __restrict__ coeff,
                 int* __restrict__ coo_cnt, int* __restrict__ coo_m,
                 int* __restrict__ coo_p, float* __restrict__ coo_v)
{
    int row = blockIdx.x;            // = m index, 0..255
    int tid = threadIdx.x;
    const float* crow = coeff + (long)row * 2048;
    float av[8];
#pragma unroll
    for (int i = 0; i < 8; ++i) av[i] = fabsf(crow[tid + 256 * i]);
    __shared__ unsigned long long red[256];
    for (int t = 0; t < 7; ++t) {
        float mx = -1.f; int mi = 0;
#pragma unroll
        for (int i = 0; i < 8; ++i) if (av[i] > mx) { mx = av[i]; mi = i; }
        unsigned col = (unsigned)(tid + 256 * mi);
        unsigned long long pk = ((unsigned long long)__float_as_uint(mx) << 32)
                              | (unsigned long long)(2048u - col); // tie -> smaller col
        red[tid] = pk; __syncthreads();
        for (int s = 128; s > 0; s >>= 1) {
            if (tid < s) { if (red[tid + s] > red[tid]) red[tid] = red[tid + s]; }
            __syncthreads();
        }
        unsigned long long w = red[0];
        __syncthreads();
        unsigned wcol = 2048u - (unsigned)(w & 0xffffffffu);
        if ((wcol & 255u) == (unsigned)tid) av[wcol >> 8] = -1.f; // consume
        if (tid == 0 && wcol < 256u) {
            int pos = atomicAdd(coo_cnt, 1);
            coo_m[pos] = row; coo_p[pos] = (int)wcol; coo_v[pos] = crow[wcol];
        }
    }
}

// ---------------- COO -> CSC (single block) ----------------
__global__ __launch_bounds__(256)
void csc_kernel(const int* __restrict__ coo_cnt, const int* __restrict__ coo_m,
                const int* __restrict__ coo_p, const float* __restrict__ coo_v,
                int* __restrict__ csc_ptr, int* __restrict__ csc_m, float* __restrict__ csc_v)
{
    __shared__ int cnt[256];
    __shared__ int off[257];
    __shared__ int cur[256];
    int tid = threadIdx.x;
    cnt[tid] = 0;
    __syncthreads();
    int n = *coo_cnt; if (n > MAXNNZ) n = MAXNNZ;
    for (int e = tid; e < n; e += 256) atomicAdd(&cnt[coo_p[e]], 1);
    __syncthreads();
    if (tid == 0) {
        int s = 0;
        for (int p = 0; p < 256; ++p) { off[p] = s; s += cnt[p]; }
        off[256] = s;
    }
    __syncthreads();
    csc_ptr[tid] = off[tid];
    if (tid == 0) csc_ptr[256] = off[256];
    cur[tid] = off[tid];
    __syncthreads();
    for (int e = tid; e < n; e += 256) {
        int p = coo_p[e];
        int pos = atomicAdd(&cur[p], 1);
        csc_m[pos] = coo_m[e];
        csc_v[pos] = coo_v[e];
    }
}

// ---------------- fp32 -> bf16 convert, 4 tensors in one launch ----------------
__global__ void cvt4_kernel(const float* a0, ushort* d0, int n0,
                            const float* a1, ushort* d1, int n1,
                            const float* a2, ushort* d2, int n2,
                            const float* a3, ushort* d3, int n3)
{
    const float* s; ushort* d; int n;
    switch (blockIdx.y) {
        case 0: s = a0; d = d0; n = n0; break;
        case 1: s = a1; d = d1; n = n1; break;
        case 2: s = a2; d = d2; n = n2; break;
        default: s = a3; d = d3; n = n3; break;
    }
    int nv = n >> 2;
    for (int i = blockIdx.x * blockDim.x + threadIdx.x; i < nv; i += gridDim.x * blockDim.x) {
        fx4 v = ((const fx4*)s)[i];
        ushort4v o;
        o[0] = f2bf(v[0]); o[1] = f2bf(v[1]); o[2] = f2bf(v[2]); o[3] = f2bf(v[3]);
        ((ushort4v*)d)[i] = o;
    }
}

// ---------------- transpose f32 [z][R][C] -> bf16 [z][C][R] ----------------
__global__ __launch_bounds__(256)
void transpose_f32_bf16(const float* __restrict__ in, ushort* __restrict__ out, int R, int C)
{
    int z = blockIdx.z;
    const float* ib = in + (long)z * R * C;
    ushort* ob = out + (long)z * R * C;
    __shared__ ushort tile[64][72];
    int r0 = blockIdx.x * 64, c0 = blockIdx.y * 64;
    int tid = threadIdx.x;
    int rl = tid >> 2, sg = tid & 3;
#pragma unroll
    for (int h = 0; h < 4; ++h) {
        fx4 v = *(const fx4*)(ib + (long)(r0 + rl) * C + c0 + h * 16 + sg * 4);
#pragma unroll
        for (int i = 0; i < 4; ++i) tile[h * 16 + sg * 4 + i][rl] = f2bf(v[i]);
    }
    __syncthreads();
    int cl = rl;
#pragma unroll
    for (int h = 0; h < 2; ++h) {
        ushort8 vv = *(const ushort8*)(&tile[cl][h * 32 + sg * 8]);
        *(ushort8*)(ob + (long)(c0 + cl) * R + r0 + h * 32 + sg * 8) = vv;
    }
}

// ---------------- transpose bf16 [z][R][C] -> bf16 [z][C][R] ----------------
__global__ __launch_bounds__(256)
void transpose_bf16(const ushort* __restrict__ in, ushort* __restrict__ out, int R, int C)
{
    int z = blockIdx.z;
    const ushort* ib = in + (long)z * R * C;
    ushort* ob = out + (long)z * R * C;
    __shared__ ushort tile[64][72];
    int r0 = blockIdx.x * 64, c0 = blockIdx.y * 64;
    int tid = threadIdx.x;
    int rl = tid >> 2, sg = tid & 3;
#pragma unroll
    for (int h = 0; h < 2; ++h) {
        ushort8 v = *(const ushort8*)(ib + (long)(r0 + rl) * C + c0 + h * 32 + sg * 8);
#pragma unroll
        for (int i = 0; i < 8; ++i) tile[h * 32 + sg * 8 + i][rl] = v[i];
    }
    __syncthreads();
    int cl = rl;
#pragma unroll
    for (int h = 0; h < 2; ++h) {
        ushort8 vv = *(const ushort8*)(&tile[cl][h * 32 + sg * 8]);
        *(ushort8*)(ob + (long)(c0 + cl) * R + r0 + h * 32 + sg * 8) = vv;
    }
}

// ---------------- NT GEMM: C[m][n] = sum_k A[m][k]*Bsrc[n][k] (+bias[m]) (*1/scale) ----
// A,Bsrc bf16; 64x64 tile; 4 waves; mfma 16x16x32 bf16.
template<int OUT_BF16, int HAS_BIAS, int HAS_SCALE>
__global__ __launch_bounds__(256)
void gemm_nt(const ushort* __restrict__ A, long long strideA,
             const ushort* __restrict__ Bm, long long strideB,
             void* __restrict__ C, long long strideC,
             const float* __restrict__ bias,
             const float* __restrict__ scale_src,
             int M, int N, int K)
{
    int z = blockIdx.z;
    const ushort* Ab = A + (long long)z * strideA;
    const ushort* Bb = Bm + (long long)z * strideB;

    int m0 = blockIdx.x * 64;
    int n0 = blockIdx.y * 64;

    __shared__ ushort As[64][40];
    __shared__ ushort Bs[64][40];

    int tid = threadIdx.x;
    int wave = tid >> 6;
    int lane = tid & 63;
    int quad = lane >> 4;
    int l16  = lane & 15;

    fx4 acc[4];
#pragma unroll
    for (int s = 0; s < 4; ++s) acc[s] = (fx4){0.f, 0.f, 0.f, 0.f};

    int r  = tid >> 2;   // 0..63
    int sg = tid & 3;    // 0..3

    for (int kc = 0; kc < K; kc += 32) {
        ushort8 av = *(const ushort8*)(Ab + (long)(m0 + r) * K + kc + sg * 8);
        ushort8 bv = *(const ushort8*)(Bb + (long)(n0 + r) * K + kc + sg * 8);
        __syncthreads();
        *(ushort8*)(&As[r][sg * 8]) = av;
        *(ushort8*)(&Bs[r][sg * 8]) = bv;
        __syncthreads();
        short8 af = *(const short8*)(&As[wave * 16 + l16][quad * 8]);
#pragma unroll
        for (int s = 0; s < 4; ++s) {
            short8 bf = *(const short8*)(&Bs[s * 16 + l16][quad * 8]);
            acc[s] = __builtin_amdgcn_mfma_f32_16x16x32_bf16(af, bf, acc[s], 0, 0, 0);
        }
    }

    float sc = 1.0f;
    if (HAS_SCALE) sc = 1.0f / scale_src[0];
#pragma unroll
    for (int s = 0; s < 4; ++s) {
#pragma unroll
        for (int rr = 0; rr < 4; ++rr) {
            int m = m0 + wave * 16 + quad * 4 + rr;
            int n = n0 + s * 16 + l16;
            float v = acc[s][rr] * sc;
            if (HAS_BIAS) v += bias[m];
            long long idx = (long long)z * strideC + (long)m * N + n;
            if (OUT_BF16) ((ushort*)C)[idx] = f2bf(v);
            else          ((float*)C)[idx] = v;
        }
    }
}

// ---------------- sparse combine + softmax: S[z][n][m] -> P[z][n][p] bf16 ----------
__global__ __launch_bounds__(256)
void spsm_kernel(const float* __restrict__ S, ushort* __restrict__ P,
                 const int* __restrict__ csc_ptr, const int* __restrict__ csc_m,
                 const float* __restrict__ csc_v)
{
    int z = blockIdx.x;
    const float* Sb = S + (long)z * 65536;
    ushort* Pb = P + (long)z * 65536;
    __shared__ float SL[16][256];
    __shared__ float TL[16][256];
    int tid = threadIdx.x;
    int e0 = csc_ptr[tid], e1 = csc_ptr[tid + 1];
    for (int t = 0; t < 16; ++t) {
        int n0 = t * 16;
#pragma unroll
        for (int i = 0; i < 16; ++i) {
            SL[i][tid] = Sb[(n0 + i) * 256 + tid];
            TL[i][tid] = 0.f;
        }
        __syncthreads();
        for (int e = e0; e < e1; ++e) {
            int m = csc_m[e]; float c = csc_v[e];
#pragma unroll
            for (int i = 0; i < 16; ++i) TL[i][tid] += SL[i][m] * c;
        }
        __syncthreads();
        // softmax: 16 groups of 16 lanes; group g handles row n0+g
        int g = tid >> 4, li = tid & 15;
        float vals[16];
        float mx = -1e30f;
#pragma unroll
        for (int u = 0; u < 16; ++u) { vals[u] = TL[g][li + 16 * u]; mx = fmaxf(mx, vals[u]); }
#pragma unroll
        for (int d = 1; d < 16; d <<= 1) mx = fmaxf(mx, __shfl_xor(mx, d, 16));
        float sum = 0.f;
#pragma unroll
        for (int u = 0; u < 16; ++u) { vals[u] = __expf(vals[u] - mx); sum += vals[u]; }
#pragma unroll
        for (int d = 1; d < 16; d <<= 1) sum += __shfl_xor(sum, d, 16);
        float inv = 1.0f / sum;
#pragma unroll
        for (int u = 0; u < 16; ++u) TL[g][li + 16 * u] = vals[u] * inv;
        __syncthreads();
#pragma unroll
        for (int i = 0; i < 16; ++i)
            Pb[(n0 + i) * 256 + tid] = f2bf(TL[i][tid]);
        __syncthreads();
    }
}

extern "C" void kernel_launch(void* const* d_in, const int* in_sizes, int n_in,
                              void* d_out, int out_size, void* d_ws, size_t ws_size,
                              hipStream_t stream)
{
    const float* x     = (const float*)d_in[0];
    const float* Wq    = (const float*)d_in[1];
    const float* bq    = (const float*)d_in[2];
    const float* Wk    = (const float*)d_in[3];
    const float* bk    = (const float*)d_in[4];
    const float* Wv    = (const float*)d_in[5];
    const float* bv    = (const float*)d_in[6];
    const float* Wo    = (const float*)d_in[7];
    const float* bo    = (const float*)d_in[8];
    const float* coeff = (const float*)d_in[9];
    const float* scale = (const float*)d_in[10];
    float* out = (float*)d_out;

    size_t o = 0;
    char* w = (char*)d_ws;
    auto take = [&](size_t bytes) -> void* {
        void* p = w + o; o += (bytes + 255) & ~(size_t)255; return p;
    };
    int*    coo_cnt = (int*)take(4);
    int*    coo_m   = (int*)take(MAXNNZ * 4);
    int*    coo_p   = (int*)take(MAXNNZ * 4);
    float*  coo_v   = (float*)take(MAXNNZ * 4);
    int*    csc_ptr = (int*)take(257 * 4);
    int*    csc_m   = (int*)take(MAXNNZ * 4);
    float*  csc_v   = (float*)take(MAXNNZ * 4);
    ushort* wqb = (ushort*)take(2048L * 512 * 2);
    ushort* wkb = (ushort*)take(2048L * 512 * 2);
    ushort* wvb = (ushort*)take(2048L * 512 * 2);
    ushort* wob = (ushort*)take(2048L * 2048 * 2);
    ushort* xT  = (ushort*)take(32L * 256 * 512 * 2);
    ushort* qb  = (ushort*)take(32L * 2048 * 256 * 2);
    ushort* kb  = (ushort*)take(32L * 2048 * 256 * 2);  // contiguous after qb
    ushort* vb  = (ushort*)take(32L * 2048 * 256 * 2);
    ushort* qbT = (ushort*)take(32L * 2048 * 256 * 2);
    ushort* kbT = (ushort*)take(32L * 2048 * 256 * 2);
    ushort* ob  = (ushort*)take(32L * 2048 * 256 * 2);
    // aliases (lifetimes disjoint):
    float*  S_ws = (float*)qb;   // 67.1 MB over qb+kb, live after q/k transposed
    ushort* P_ws = qbT;          // live after S-GEMM consumed qbT
    ushort* obT  = kbT;          // live after S-GEMM consumed kbT
    (void)in_sizes; (void)n_in; (void)out_size; (void)ws_size;

    // 1) sparsity structure
    hipMemsetAsync(coo_cnt, 0, 4, stream);
    topk_kernel<<<256, 256, 0, stream>>>(coeff, coo_cnt, coo_m, coo_p, coo_v);
    csc_kernel<<<1, 256, 0, stream>>>(coo_cnt, coo_m, coo_p, coo_v, csc_ptr, csc_m, csc_v);

    // 2) weight converts + x transpose (f32 [b][512][256] -> bf16 [b][256][512])
    cvt4_kernel<<<dim3(1024, 4, 1), 256, 0, stream>>>(
        Wq, wqb, 2048 * 512, Wk, wkb, 2048 * 512, Wv, wvb, 2048 * 512, Wo, wob, 2048 * 2048);
    transpose_f32_bf16<<<dim3(8, 4, 32), 256, 0, stream>>>(x, xT, 512, 256);

    // 3) QKV projections: [2048,512] x [256,512]^T per batch -> bf16 [b][2048][256]
    dim3 gqkv(32, 4, 32);
    gemm_nt<1, 1, 0><<<gqkv, 256, 0, stream>>>(wqb, 0, xT, 256LL * 512, qb, 2048LL * 256,
                                               bq, nullptr, 2048, 256, 512);
    gemm_nt<1, 1, 0><<<gqkv, 256, 0, stream>>>(wkb, 0, xT, 256LL * 512, kb, 2048LL * 256,
                                               bk, nullptr, 2048, 256, 512);
    gemm_nt<1, 1, 0><<<gqkv, 256, 0, stream>>>(wvb, 0, xT, 256LL * 512, vb, 2048LL * 256,
                                               bv, nullptr, 2048, 256, 512);

    // 4) per-(b,h) transposes of q,k: [d][n] -> [n][d]
    transpose_bf16<<<dim3(4, 4, 256), 256, 0, stream>>>(qb, qbT, 256, 256);
    transpose_bf16<<<dim3(4, 4, 256), 256, 0, stream>>>(kb, kbT, 256, 256);

    // 5) S = Q^T K / scale  -> f32 [z][n][m]
    gemm_nt<0, 0, 1><<<dim3(4, 4, 256), 256, 0, stream>>>(qbT, 65536, kbT, 65536,
                                                          S_ws, 65536, nullptr, scale,
                                                          256, 256, 256);

    // 6) sparse combine + softmax -> P bf16 [z][n][p]
    spsm_kernel<<<256, 256, 0, stream>>>(S_ws, P_ws, csc_ptr, csc_m, csc_v);

    // 7) O[d][n] = sum_p V[d][p] P[n][p] -> ob bf16 [b][2048][256]
    gemm_nt<1, 0, 0><<<dim3(4, 4, 256), 256, 0, stream>>>(vb, 65536, P_ws, 65536,
                                                          ob, 65536, nullptr, nullptr,
                                                          256, 256, 256);

    // 8) ob [b][2048][256] -> obT [b][256][2048]
    transpose_bf16<<<dim3(32, 4, 32), 256, 0, stream>>>(ob, obT, 2048, 256);

    // 9) final projection: out[b][i][n] = sum_o Wo[i][o] ob[b][o][n] + bo[i], f32 out
    gemm_nt<0, 1, 0><<<dim3(32, 4, 32), 256, 0, stream>>>(wob, 0, obT, 256LL * 2048,
                                                          out, 2048LL * 256, bo, nullptr,
                                                          2048, 256, 2048);
}

// Round 3
// 512.452 us; speedup vs baseline: 1.1222x; 1.1222x over previous
//
#include <hip/hip_runtime.h>

typedef unsigned short ushort;
typedef __attribute__((ext_vector_type(8))) short short8;
typedef __attribute__((ext_vector_type(8))) unsigned short ushort8;
typedef __attribute__((ext_vector_type(4))) unsigned short ushort4v;
typedef __attribute__((ext_vector_type(4))) float fx4;

#define MAXNNZ (256*7)

__device__ __forceinline__ ushort f2bf(float f) {
    union { float f; unsigned u; } v; v.f = f;
    unsigned r = v.u + 0x7fffu + ((v.u >> 16) & 1u);
    return (ushort)(r >> 16);
}

// ---------------- top-7 per row of coeff (rows 0..255), emit COO for cols<256 -----
__global__ __launch_bounds__(256)
void topk_kernel(const float* __restrict__ coeff,
                 int* __restrict__ coo_cnt, int* __restrict__ coo_m,
                 int* __restrict__ coo_p, float* __restrict__ coo_v)
{
    int row = blockIdx.x;            // = m index, 0..255
    int tid = threadIdx.x;
    const float* crow = coeff + (long)row * 2048;
    float av[8];
#pragma unroll
    for (int i = 0; i < 8; ++i) av[i] = fabsf(crow[tid + 256 * i]);
    __shared__ unsigned long long red[256];
    for (int t = 0; t < 7; ++t) {
        float mx = -1.f; int mi = 0;
#pragma unroll
        for (int i = 0; i < 8; ++i) if (av[i] > mx) { mx = av[i]; mi = i; }
        unsigned col = (unsigned)(tid + 256 * mi);
        unsigned long long pk = ((unsigned long long)__float_as_uint(mx) << 32)
                              | (unsigned long long)(2048u - col); // tie -> smaller col
        red[tid] = pk; __syncthreads();
        for (int s = 128; s > 0; s >>= 1) {
            if (tid < s) { if (red[tid + s] > red[tid]) red[tid] = red[tid + s]; }
            __syncthreads();
        }
        unsigned long long w = red[0];
        __syncthreads();
        unsigned wcol = 2048u - (unsigned)(w & 0xffffffffu);
        if ((wcol & 255u) == (unsigned)tid) av[wcol >> 8] = -1.f; // consume
        if (tid == 0 && wcol < 256u) {
            int pos = atomicAdd(coo_cnt, 1);
            coo_m[pos] = row; coo_p[pos] = (int)wcol; coo_v[pos] = crow[wcol];
        }
    }
}

// ---------------- COO -> CSC (single block) ----------------
__global__ __launch_bounds__(256)
void csc_kernel(const int* __restrict__ coo_cnt, const int* __restrict__ coo_m,
                const int* __restrict__ coo_p, const float* __restrict__ coo_v,
                int* __restrict__ csc_ptr, int* __restrict__ csc_m, float* __restrict__ csc_v)
{
    __shared__ int cnt[256];
    __shared__ int off[257];
    __shared__ int cur[256];
    int tid = threadIdx.x;
    cnt[tid] = 0;
    __syncthreads();
    int n = *coo_cnt; if (n > MAXNNZ) n = MAXNNZ;
    for (int e = tid; e < n; e += 256) atomicAdd(&cnt[coo_p[e]], 1);
    __syncthreads();
    if (tid == 0) {
        int s = 0;
        for (int p = 0; p < 256; ++p) { off[p] = s; s += cnt[p]; }
        off[256] = s;
    }
    __syncthreads();
    csc_ptr[tid] = off[tid];
    if (tid == 0) csc_ptr[256] = off[256];
    cur[tid] = off[tid];
    __syncthreads();
    for (int e = tid; e < n; e += 256) {
        int p = coo_p[e];
        int pos = atomicAdd(&cur[p], 1);
        csc_m[pos] = coo_m[e];
        csc_v[pos] = coo_v[e];
    }
}

// ---------------- fp32 -> bf16 convert, 4 tensors in one launch ----------------
__global__ void cvt4_kernel(const float* a0, ushort* d0, int n0,
                            const float* a1, ushort* d1, int n1,
                            const float* a2, ushort* d2, int n2,
                            const float* a3, ushort* d3, int n3)
{
    const float* s; ushort* d; int n;
    switch (blockIdx.y) {
        case 0: s = a0; d = d0; n = n0; break;
        case 1: s = a1; d = d1; n = n1; break;
        case 2: s = a2; d = d2; n = n2; break;
        default: s = a3; d = d3; n = n3; break;
    }
    int nv = n >> 2;
    for (int i = blockIdx.x * blockDim.x + threadIdx.x; i < nv; i += gridDim.x * blockDim.x) {
        fx4 v = ((const fx4*)s)[i];
        ushort4v o;
        o[0] = f2bf(v[0]); o[1] = f2bf(v[1]); o[2] = f2bf(v[2]); o[3] = f2bf(v[3]);
        ((ushort4v*)d)[i] = o;
    }
}

// ---------------- transpose f32 [z][R][C] -> bf16 [z][C][R] ----------------
__global__ __launch_bounds__(256)
void transpose_f32_bf16(const float* __restrict__ in, ushort* __restrict__ out, int R, int C)
{
    int z = blockIdx.z;
    const float* ib = in + (long)z * R * C;
    ushort* ob = out + (long)z * R * C;
    __shared__ ushort tile[64][72];
    int r0 = blockIdx.x * 64, c0 = blockIdx.y * 64;
    int tid = threadIdx.x;
    int rl = tid >> 2, sg = tid & 3;
#pragma unroll
    for (int h = 0; h < 4; ++h) {
        fx4 v = *(const fx4*)(ib + (long)(r0 + rl) * C + c0 + h * 16 + sg * 4);
#pragma unroll
        for (int i = 0; i < 4; ++i) tile[h * 16 + sg * 4 + i][rl] = f2bf(v[i]);
    }
    __syncthreads();
    int cl = rl;
#pragma unroll
    for (int h = 0; h < 2; ++h) {
        ushort8 vv = *(const ushort8*)(&tile[cl][h * 32 + sg * 8]);
        *(ushort8*)(ob + (long)(c0 + cl) * R + r0 + h * 32 + sg * 8) = vv;
    }
}

// ---------------- 128x128-tile NT GEMM (m93 structure: reg->ds_write staging) ------
// C[m][n] = sum_k A[m][k]*B[n][k]  (+bias[m]) (*1/scale)
// MODE 0: f32 out, idx = z*strideC + m*N + n
// MODE 1: bf16 out, idx = z*strideC + m*N + n
// MODE 2: bf16 out, qk-transposed-head: idx = z*524288 + (m>>8)*65536 + n*256 + (m&255)
// MODE 3: bf16 out, obT: idx = (z>>3)*524288 + n*2048 + (z&7)*256 + m
template<int MODE, int HAS_BIAS, int HAS_SCALE>
__global__ __launch_bounds__(256)
void gemm128(const ushort* __restrict__ A, long long strideA,
             const ushort* __restrict__ B, long long strideB,
             void* __restrict__ C, long long strideC,
             const float* __restrict__ bias, const float* __restrict__ scale_src,
             int M, int N, int K)
{
    int z = blockIdx.z;
    const ushort* Ab = A + (long long)z * strideA;
    const ushort* Bb = B + (long long)z * strideB;
    int m0 = blockIdx.x * 128, n0 = blockIdx.y * 128;

    __shared__ __align__(16) ushort As[128 * 32];
    __shared__ __align__(16) ushort Bs[128 * 32];

    int tid = threadIdx.x;
    int wave = tid >> 6, lane = tid & 63;
    int wrow = wave >> 1, wcol = wave & 1;
    int l16 = lane & 15, quad = lane >> 4;

    fx4 acc[4][4];
#pragma unroll
    for (int i = 0; i < 4; ++i)
#pragma unroll
        for (int j = 0; j < 4; ++j) acc[i][j] = (fx4){0.f, 0.f, 0.f, 0.f};

    int r  = tid >> 2;   // 0..63
    int sg = tid & 3;    // 0..3 (k-quarter)
    const ushort* gA = Ab + (long)(m0 + r) * K + sg * 8;
    const ushort* gB = Bb + (long)(n0 + r) * K + sg * 8;
    ushort* wAs0 = As + r * 32 + sg * 8;
    ushort* wAs1 = As + (64 + r) * 32 + sg * 8;
    ushort* wBs0 = Bs + r * 32 + sg * 8;
    ushort* wBs1 = Bs + (64 + r) * 32 + sg * 8;

    for (int kc = 0; kc < K; kc += 32) {
        // global loads first: independent of LDS, overlap prev iter's MFMAs
        ushort8 a0 = *(const ushort8*)(gA + kc);
        ushort8 a1 = *(const ushort8*)(gA + (long)64 * K + kc);
        ushort8 b0 = *(const ushort8*)(gB + kc);
        ushort8 b1 = *(const ushort8*)(gB + (long)64 * K + kc);
        __syncthreads();                       // prev iter frag reads done
        *(ushort8*)wAs0 = a0;
        *(ushort8*)wAs1 = a1;
        *(ushort8*)wBs0 = b0;
        *(ushort8*)wBs1 = b1;
        __syncthreads();                       // tiles visible to all waves

        short8 af[4], bf[4];
#pragma unroll
        for (int i = 0; i < 4; ++i)
            af[i] = *(const short8*)(As + (wrow * 64 + i * 16 + l16) * 32 + quad * 8);
#pragma unroll
        for (int j = 0; j < 4; ++j)
            bf[j] = *(const short8*)(Bs + (wcol * 64 + j * 16 + l16) * 32 + quad * 8);
#pragma unroll
        for (int i = 0; i < 4; ++i)
#pragma unroll
            for (int j = 0; j < 4; ++j)
                acc[i][j] = __builtin_amdgcn_mfma_f32_16x16x32_bf16(af[i], bf[j], acc[i][j], 0, 0, 0);
    }

    float sc = 1.0f;
    if (HAS_SCALE) sc = 1.0f / scale_src[0];
#pragma unroll
    for (int i = 0; i < 4; ++i) {
#pragma unroll
        for (int j = 0; j < 4; ++j) {
#pragma unroll
            for (int r2 = 0; r2 < 4; ++r2) {
                int m = m0 + wrow * 64 + i * 16 + quad * 4 + r2;
                int n = n0 + wcol * 64 + j * 16 + l16;
                float v = acc[i][j][r2] * sc;
                if (HAS_BIAS) v += bias[m];
                if (MODE == 0) {
                    ((float*)C)[(long long)z * strideC + (long)m * N + n] = v;
                } else if (MODE == 1) {
                    ((ushort*)C)[(long long)z * strideC + (long)m * N + n] = f2bf(v);
                } else if (MODE == 2) {
                    ((ushort*)C)[(long long)z * 524288 + (long)(m >> 8) * 65536
                                 + (long)n * 256 + (m & 255)] = f2bf(v);
                } else {
                    ((ushort*)C)[((long long)(z >> 3)) * 524288 + (long)n * 2048
                                 + (z & 7) * 256 + m] = f2bf(v);
                }
            }
        }
    }
}

// ---------------- sparse combine + softmax: S[z][n][m] -> P[z][n][p] bf16 ----------
__global__ __launch_bounds__(256)
void spsm_kernel(const float* __restrict__ S, ushort* __restrict__ P,
                 const int* __restrict__ csc_ptr, const int* __restrict__ csc_m,
                 const float* __restrict__ csc_v)
{
    int z = blockIdx.x;
    const float* Sb = S + (long)z * 65536;
    ushort* Pb = P + (long)z * 65536;
    __shared__ float SL[16][256];
    __shared__ float TL[16][256];
    int tid = threadIdx.x;
    int e0 = csc_ptr[tid], e1 = csc_ptr[tid + 1];
    for (int t = 0; t < 16; ++t) {
        int n0 = t * 16;
#pragma unroll
        for (int i = 0; i < 16; ++i) {
            SL[i][tid] = Sb[(n0 + i) * 256 + tid];
            TL[i][tid] = 0.f;
        }
        __syncthreads();
        for (int e = e0; e < e1; ++e) {
            int m = csc_m[e]; float c = csc_v[e];
#pragma unroll
            for (int i = 0; i < 16; ++i) TL[i][tid] += SL[i][m] * c;
        }
        __syncthreads();
        // softmax: 16 groups of 16 lanes; group g handles row n0+g
        int g = tid >> 4, li = tid & 15;
        float vals[16];
        float mx = -1e30f;
#pragma unroll
        for (int u = 0; u < 16; ++u) { vals[u] = TL[g][li + 16 * u]; mx = fmaxf(mx, vals[u]); }
#pragma unroll
        for (int d = 1; d < 16; d <<= 1) mx = fmaxf(mx, __shfl_xor(mx, d, 16));
        float sum = 0.f;
#pragma unroll
        for (int u = 0; u < 16; ++u) { vals[u] = __expf(vals[u] - mx); sum += vals[u]; }
#pragma unroll
        for (int d = 1; d < 16; d <<= 1) sum += __shfl_xor(sum, d, 16);
        float inv = 1.0f / sum;
#pragma unroll
        for (int u = 0; u < 16; ++u) TL[g][li + 16 * u] = vals[u] * inv;
        __syncthreads();
#pragma unroll
        for (int i = 0; i < 16; ++i)
            Pb[(n0 + i) * 256 + tid] = f2bf(TL[i][tid]);
        __syncthreads();
    }
}

extern "C" void kernel_launch(void* const* d_in, const int* in_sizes, int n_in,
                              void* d_out, int out_size, void* d_ws, size_t ws_size,
                              hipStream_t stream)
{
    const float* x     = (const float*)d_in[0];
    const float* Wq    = (const float*)d_in[1];
    const float* bq    = (const float*)d_in[2];
    const float* Wk    = (const float*)d_in[3];
    const float* bk    = (const float*)d_in[4];
    const float* Wv    = (const float*)d_in[5];
    const float* bv    = (const float*)d_in[6];
    const float* Wo    = (const float*)d_in[7];
    const float* bo    = (const float*)d_in[8];
    const float* coeff = (const float*)d_in[9];
    const float* scale = (const float*)d_in[10];
    float* out = (float*)d_out;

    size_t o = 0;
    char* w = (char*)d_ws;
    auto take = [&](size_t bytes) -> void* {
        void* p = w + o; o += (bytes + 255) & ~(size_t)255; return p;
    };
    int*    coo_cnt = (int*)take(4);
    int*    coo_m   = (int*)take(MAXNNZ * 4);
    int*    coo_p   = (int*)take(MAXNNZ * 4);
    float*  coo_v   = (float*)take(MAXNNZ * 4);
    int*    csc_ptr = (int*)take(257 * 4);
    int*    csc_m   = (int*)take(MAXNNZ * 4);
    float*  csc_v   = (float*)take(MAXNNZ * 4);
    ushort* wqb = (ushort*)take(2048L * 512 * 2);
    ushort* wkb = (ushort*)take(2048L * 512 * 2);
    ushort* wvb = (ushort*)take(2048L * 512 * 2);
    ushort* wob = (ushort*)take(2048L * 2048 * 2);
    ushort* xT  = (ushort*)take(32L * 256 * 512 * 2);
    ushort* qbT = (ushort*)take(32L * 2048 * 256 * 2);   // [b][h][n][d]
    ushort* kbT = (ushort*)take(32L * 2048 * 256 * 2);   // [b][h][n][d]
    ushort* vb  = (ushort*)take(32L * 2048 * 256 * 2);   // [b][2048][256]
    float*  S_ws = (float*)take(256L * 65536 * 4);       // [z][n][m] f32
    // aliases (lifetimes disjoint):
    ushort* P_ws = kbT;   // kbT dead after S-GEMM; spsm writes P, PV reads it
    ushort* obT  = qbT;   // qbT dead after S-GEMM; PV writes obT, final reads it
    (void)in_sizes; (void)n_in; (void)out_size; (void)ws_size;

    // 1) sparsity structure
    hipMemsetAsync(coo_cnt, 0, 4, stream);
    topk_kernel<<<256, 256, 0, stream>>>(coeff, coo_cnt, coo_m, coo_p, coo_v);
    csc_kernel<<<1, 256, 0, stream>>>(coo_cnt, coo_m, coo_p, coo_v, csc_ptr, csc_m, csc_v);

    // 2) weight converts + x transpose (f32 [b][512][256] -> bf16 [b][256][512])
    cvt4_kernel<<<dim3(1024, 4, 1), 256, 0, stream>>>(
        Wq, wqb, 2048 * 512, Wk, wkb, 2048 * 512, Wv, wvb, 2048 * 512, Wo, wob, 2048 * 2048);
    transpose_f32_bf16<<<dim3(8, 4, 32), 256, 0, stream>>>(x, xT, 512, 256);

    // 3) QKV projections (q,k written directly as [b][h][n][d]; v as [b][2048][256])
    gemm128<2, 1, 0><<<dim3(16, 2, 32), 256, 0, stream>>>(
        wqb, 0, xT, 256LL * 512, qbT, 0, bq, nullptr, 2048, 256, 512);
    gemm128<2, 1, 0><<<dim3(16, 2, 32), 256, 0, stream>>>(
        wkb, 0, xT, 256LL * 512, kbT, 0, bk, nullptr, 2048, 256, 512);
    gemm128<1, 1, 0><<<dim3(16, 2, 32), 256, 0, stream>>>(
        wvb, 0, xT, 256LL * 512, vb, 2048LL * 256, bv, nullptr, 2048, 256, 512);

    // 4) S = Q^T K / scale  -> f32 [z][n][m]
    gemm128<0, 0, 1><<<dim3(2, 2, 256), 256, 0, stream>>>(
        qbT, 65536, kbT, 65536, S_ws, 65536, nullptr, scale, 256, 256, 256);

    // 5) sparse combine + softmax -> P bf16 [z][n][p]
    spsm_kernel<<<256, 256, 0, stream>>>(S_ws, P_ws, csc_ptr, csc_m, csc_v);

    // 6) O[d][n] = sum_p V[d][p] P[n][p], written directly as obT [b][n][2048]
    gemm128<3, 0, 0><<<dim3(2, 2, 256), 256, 0, stream>>>(
        vb, 65536, P_ws, 65536, obT, 0, nullptr, nullptr, 256, 256, 256);

    // 7) final projection: out[b][i][n] = sum_o Wo[i][o] obT[b][n][o] + bo[i], f32 out
    gemm128<0, 1, 0><<<dim3(16, 2, 32), 256, 0, stream>>>(
        wob, 0, obT, 256LL * 2048, out, 2048LL * 256, bo, nullptr, 2048, 256, 2048);
}

// Round 4
// 505.898 us; speedup vs baseline: 1.1367x; 1.0130x over previous
//
#include <hip/hip_runtime.h>

typedef unsigned short ushort;
typedef __attribute__((ext_vector_type(8))) short short8;
typedef __attribute__((ext_vector_type(8))) unsigned short ushort8;
typedef __attribute__((ext_vector_type(4))) unsigned short ushort4v;
typedef __attribute__((ext_vector_type(4))) float fx4;

#define MAXNNZ (256*7)

__device__ __forceinline__ ushort f2bf(float f) {
    union { float f; unsigned u; } v; v.f = f;
    unsigned r = v.u + 0x7fffu + ((v.u >> 16) & 1u);
    return (ushort)(r >> 16);
}

// async global->LDS, 16B per lane; LDS dest = wave-uniform base + lane*16
__device__ __forceinline__ void gload_lds16(const ushort* g, ushort* l) {
    __builtin_amdgcn_global_load_lds(
        (const __attribute__((address_space(1))) unsigned int*)g,
        (__attribute__((address_space(3))) unsigned int*)l, 16, 0, 0);
}

// ---------------- top-7 per row of coeff (rows 0..255), emit COO for cols<256 -----
__global__ __launch_bounds__(256)
void topk_kernel(const float* __restrict__ coeff,
                 int* __restrict__ coo_cnt, int* __restrict__ coo_m,
                 int* __restrict__ coo_p, float* __restrict__ coo_v)
{
    int row = blockIdx.x;            // = m index, 0..255
    int tid = threadIdx.x;
    const float* crow = coeff + (long)row * 2048;
    float av[8];
#pragma unroll
    for (int i = 0; i < 8; ++i) av[i] = fabsf(crow[tid + 256 * i]);
    __shared__ unsigned long long red[256];
    for (int t = 0; t < 7; ++t) {
        float mx = -1.f; int mi = 0;
#pragma unroll
        for (int i = 0; i < 8; ++i) if (av[i] > mx) { mx = av[i]; mi = i; }
        unsigned col = (unsigned)(tid + 256 * mi);
        unsigned long long pk = ((unsigned long long)__float_as_uint(mx) << 32)
                              | (unsigned long long)(2048u - col); // tie -> smaller col
        red[tid] = pk; __syncthreads();
        for (int s = 128; s > 0; s >>= 1) {
            if (tid < s) { if (red[tid + s] > red[tid]) red[tid] = red[tid + s]; }
            __syncthreads();
        }
        unsigned long long w = red[0];
        __syncthreads();
        unsigned wcol = 2048u - (unsigned)(w & 0xffffffffu);
        if ((wcol & 255u) == (unsigned)tid) av[wcol >> 8] = -1.f; // consume
        if (tid == 0 && wcol < 256u) {
            int pos = atomicAdd(coo_cnt, 1);
            coo_m[pos] = row; coo_p[pos] = (int)wcol; coo_v[pos] = crow[wcol];
        }
    }
}

// ---------------- COO -> CSC (single block) ----------------
__global__ __launch_bounds__(256)
void csc_kernel(const int* __restrict__ coo_cnt, const int* __restrict__ coo_m,
                const int* __restrict__ coo_p, const float* __restrict__ coo_v,
                int* __restrict__ csc_ptr, int* __restrict__ csc_m, float* __restrict__ csc_v)
{
    __shared__ int cnt[256];
    __shared__ int off[257];
    __shared__ int cur[256];
    int tid = threadIdx.x;
    cnt[tid] = 0;
    __syncthreads();
    int n = *coo_cnt; if (n > MAXNNZ) n = MAXNNZ;
    for (int e = tid; e < n; e += 256) atomicAdd(&cnt[coo_p[e]], 1);
    __syncthreads();
    if (tid == 0) {
        int s = 0;
        for (int p = 0; p < 256; ++p) { off[p] = s; s += cnt[p]; }
        off[256] = s;
    }
    __syncthreads();
    csc_ptr[tid] = off[tid];
    if (tid == 0) csc_ptr[256] = off[256];
    cur[tid] = off[tid];
    __syncthreads();
    for (int e = tid; e < n; e += 256) {
        int p = coo_p[e];
        int pos = atomicAdd(&cur[p], 1);
        csc_m[pos] = coo_m[e];
        csc_v[pos] = coo_v[e];
    }
}

// ---------------- fp32 -> bf16 convert, 4 tensors in one launch ----------------
__global__ void cvt4_kernel(const float* a0, ushort* d0, int n0,
                            const float* a1, ushort* d1, int n1,
                            const float* a2, ushort* d2, int n2,
                            const float* a3, ushort* d3, int n3)
{
    const float* s; ushort* d; int n;
    switch (blockIdx.y) {
        case 0: s = a0; d = d0; n = n0; break;
        case 1: s = a1; d = d1; n = n1; break;
        case 2: s = a2; d = d2; n = n2; break;
        default: s = a3; d = d3; n = n3; break;
    }
    int nv = n >> 2;
    for (int i = blockIdx.x * blockDim.x + threadIdx.x; i < nv; i += gridDim.x * blockDim.x) {
        fx4 v = ((const fx4*)s)[i];
        ushort4v o;
        o[0] = f2bf(v[0]); o[1] = f2bf(v[1]); o[2] = f2bf(v[2]); o[3] = f2bf(v[3]);
        ((ushort4v*)d)[i] = o;
    }
}

// ---------------- transpose f32 [z][R][C] -> bf16 [z][C][R] ----------------
__global__ __launch_bounds__(256)
void transpose_f32_bf16(const float* __restrict__ in, ushort* __restrict__ out, int R, int C)
{
    int z = blockIdx.z;
    const float* ib = in + (long)z * R * C;
    ushort* ob = out + (long)z * R * C;
    __shared__ ushort tile[64][72];
    int r0 = blockIdx.x * 64, c0 = blockIdx.y * 64;
    int tid = threadIdx.x;
    int rl = tid >> 2, sg = tid & 3;
#pragma unroll
    for (int h = 0; h < 4; ++h) {
        fx4 v = *(const fx4*)(ib + (long)(r0 + rl) * C + c0 + h * 16 + sg * 4);
#pragma unroll
        for (int i = 0; i < 4; ++i) tile[h * 16 + sg * 4 + i][rl] = f2bf(v[i]);
    }
    __syncthreads();
    int cl = rl;
#pragma unroll
    for (int h = 0; h < 2; ++h) {
        ushort8 vv = *(const ushort8*)(&tile[cl][h * 32 + sg * 8]);
        *(ushort8*)(ob + (long)(c0 + cl) * R + r0 + h * 32 + sg * 8) = vv;
    }
}

// ---------------- 128x128-tile NT GEMM (m97 structure: global_load_lds staging) ----
// C[m][n] = sum_k A[m][k]*B[n][k]  (+bias[m]) (*1/scale)
// MODE 0: f32 out, idx = z*strideC + m*N + n
// MODE 1: bf16 out, idx = z*strideC + m*N + n
// MODE 2: bf16 out, qk-transposed-head: idx = z*524288 + (m>>8)*65536 + n*256 + (m&255)
// MODE 3: bf16 out, obT: idx = (z>>3)*524288 + n*2048 + (z&7)*256 + m
template<int MODE, int HAS_BIAS, int HAS_SCALE>
__global__ __launch_bounds__(256)
void gemm128(const ushort* __restrict__ A, long long strideA,
             const ushort* __restrict__ B, long long strideB,
             void* __restrict__ C, long long strideC,
             const float* __restrict__ bias, const float* __restrict__ scale_src,
             int M, int N, int K)
{
    int z = blockIdx.z;
    const ushort* Ab = A + (long long)z * strideA;
    const ushort* Bb = B + (long long)z * strideB;
    int m0 = blockIdx.x * 128, n0 = blockIdx.y * 128;

    __shared__ __align__(16) ushort As[128 * 32];
    __shared__ __align__(16) ushort Bs[128 * 32];

    int tid = threadIdx.x;
    int wave = tid >> 6, lane = tid & 63;
    int wrow = wave >> 1, wcol = wave & 1;
    int l16 = lane & 15, quad = lane >> 4;
    int lrow = lane >> 2, lkq = lane & 3;   // staging: row-in-wave-chunk, k-quarter

    fx4 acc[4][4];
#pragma unroll
    for (int i = 0; i < 4; ++i)
#pragma unroll
        for (int j = 0; j < 4; ++j) acc[i][j] = (fx4){0.f, 0.f, 0.f, 0.f};

    // staging: wave w covers rows [w*16, w*16+16) and [64+w*16, ...) of the tile;
    // lane i -> row w*16 + (i>>2), k-bytes (i&3)*16. LDS dest = uniform base + lane*16,
    // which matches As row-major [128][32] (row stride 64 B).
    const ushort* gA0 = Ab + (long)(m0 + wave * 16 + lrow) * K + lkq * 8;
    const ushort* gA1 = gA0 + (long)64 * K;
    const ushort* gB0 = Bb + (long)(n0 + wave * 16 + lrow) * K + lkq * 8;
    const ushort* gB1 = gB0 + (long)64 * K;
    ushort* lA0 = As + (wave * 16) * 32;
    ushort* lA1 = As + (64 + wave * 16) * 32;
    ushort* lB0 = Bs + (wave * 16) * 32;
    ushort* lB1 = Bs + (64 + wave * 16) * 32;

    for (int kc = 0; kc < K; kc += 32) {
        __syncthreads();                       // prev iter frag reads done
        gload_lds16(gA0 + kc, lA0);
        gload_lds16(gA1 + kc, lA1);
        gload_lds16(gB0 + kc, lB0);
        gload_lds16(gB1 + kc, lB1);
        __syncthreads();                       // drains vmcnt(0): LDS tiles ready

        short8 af[4], bf[4];
#pragma unroll
        for (int i = 0; i < 4; ++i)
            af[i] = *(const short8*)(As + (wrow * 64 + i * 16 + l16) * 32 + quad * 8);
#pragma unroll
        for (int j = 0; j < 4; ++j)
            bf[j] = *(const short8*)(Bs + (wcol * 64 + j * 16 + l16) * 32 + quad * 8);
#pragma unroll
        for (int i = 0; i < 4; ++i)
#pragma unroll
            for (int j = 0; j < 4; ++j)
                acc[i][j] = __builtin_amdgcn_mfma_f32_16x16x32_bf16(af[i], bf[j], acc[i][j], 0, 0, 0);
    }

    float sc = 1.0f;
    if (HAS_SCALE) sc = 1.0f / scale_src[0];
#pragma unroll
    for (int i = 0; i < 4; ++i) {
#pragma unroll
        for (int j = 0; j < 4; ++j) {
#pragma unroll
            for (int r2 = 0; r2 < 4; ++r2) {
                int m = m0 + wrow * 64 + i * 16 + quad * 4 + r2;
                int n = n0 + wcol * 64 + j * 16 + l16;
                float v = acc[i][j][r2] * sc;
                if (HAS_BIAS) v += bias[m];
                if (MODE == 0) {
                    ((float*)C)[(long long)z * strideC + (long)m * N + n] = v;
                } else if (MODE == 1) {
                    ((ushort*)C)[(long long)z * strideC + (long)m * N + n] = f2bf(v);
                } else if (MODE == 2) {
                    ((ushort*)C)[(long long)z * 524288 + (long)(m >> 8) * 65536
                                 + (long)n * 256 + (m & 255)] = f2bf(v);
                } else {
                    ((ushort*)C)[((long long)(z >> 3)) * 524288 + (long)n * 2048
                                 + (z & 7) * 256 + m] = f2bf(v);
                }
            }
        }
    }
}

// ---------------- sparse combine + softmax: S[z][n][m] -> P[z][n][p] bf16 ----------
__global__ __launch_bounds__(256)
void spsm_kernel(const float* __restrict__ S, ushort* __restrict__ P,
                 const int* __restrict__ csc_ptr, const int* __restrict__ csc_m,
                 const float* __restrict__ csc_v)
{
    int z = blockIdx.x;
    const float* Sb = S + (long)z * 65536;
    ushort* Pb = P + (long)z * 65536;
    __shared__ float SL[16][256];
    __shared__ float TL[16][256];
    int tid = threadIdx.x;
    int e0 = csc_ptr[tid], e1 = csc_ptr[tid + 1];
    for (int t = 0; t < 16; ++t) {
        int n0 = t * 16;
#pragma unroll
        for (int i = 0; i < 16; ++i) {
            SL[i][tid] = Sb[(n0 + i) * 256 + tid];
            TL[i][tid] = 0.f;
        }
        __syncthreads();
        for (int e = e0; e < e1; ++e) {
            int m = csc_m[e]; float c = csc_v[e];
#pragma unroll
            for (int i = 0; i < 16; ++i) TL[i][tid] += SL[i][m] * c;
        }
        __syncthreads();
        // softmax: 16 groups of 16 lanes; group g handles row n0+g
        int g = tid >> 4, li = tid & 15;
        float vals[16];
        float mx = -1e30f;
#pragma unroll
        for (int u = 0; u < 16; ++u) { vals[u] = TL[g][li + 16 * u]; mx = fmaxf(mx, vals[u]); }
#pragma unroll
        for (int d = 1; d < 16; d <<= 1) mx = fmaxf(mx, __shfl_xor(mx, d, 16));
        float sum = 0.f;
#pragma unroll
        for (int u = 0; u < 16; ++u) { vals[u] = __expf(vals[u] - mx); sum += vals[u]; }
#pragma unroll
        for (int d = 1; d < 16; d <<= 1) sum += __shfl_xor(sum, d, 16);
        float inv = 1.0f / sum;
#pragma unroll
        for (int u = 0; u < 16; ++u) TL[g][li + 16 * u] = vals[u] * inv;
        __syncthreads();
#pragma unroll
        for (int i = 0; i < 16; ++i)
            Pb[(n0 + i) * 256 + tid] = f2bf(TL[i][tid]);
        __syncthreads();
    }
}

extern "C" void kernel_launch(void* const* d_in, const int* in_sizes, int n_in,
                              void* d_out, int out_size, void* d_ws, size_t ws_size,
                              hipStream_t stream)
{
    const float* x     = (const float*)d_in[0];
    const float* Wq    = (const float*)d_in[1];
    const float* bq    = (const float*)d_in[2];
    const float* Wk    = (const float*)d_in[3];
    const float* bk    = (const float*)d_in[4];
    const float* Wv    = (const float*)d_in[5];
    const float* bv    = (const float*)d_in[6];
    const float* Wo    = (const float*)d_in[7];
    const float* bo    = (const float*)d_in[8];
    const float* coeff = (const float*)d_in[9];
    const float* scale = (const float*)d_in[10];
    float* out = (float*)d_out;

    size_t o = 0;
    char* w = (char*)d_ws;
    auto take = [&](size_t bytes) -> void* {
        void* p = w + o; o += (bytes + 255) & ~(size_t)255; return p;
    };
    int*    coo_cnt = (int*)take(4);
    int*    coo_m   = (int*)take(MAXNNZ * 4);
    int*    coo_p   = (int*)take(MAXNNZ * 4);
    float*  coo_v   = (float*)take(MAXNNZ * 4);
    int*    csc_ptr = (int*)take(257 * 4);
    int*    csc_m   = (int*)take(MAXNNZ * 4);
    float*  csc_v   = (float*)take(MAXNNZ * 4);
    ushort* wqb = (ushort*)take(2048L * 512 * 2);
    ushort* wkb = (ushort*)take(2048L * 512 * 2);
    ushort* wvb = (ushort*)take(2048L * 512 * 2);
    ushort* wob = (ushort*)take(2048L * 2048 * 2);
    ushort* xT  = (ushort*)take(32L * 256 * 512 * 2);
    ushort* qbT = (ushort*)take(32L * 2048 * 256 * 2);   // [b][h][n][d]
    ushort* kbT = (ushort*)take(32L * 2048 * 256 * 2);   // [b][h][n][d]
    ushort* vb  = (ushort*)take(32L * 2048 * 256 * 2);   // [b][2048][256]
    float*  S_ws = (float*)take(256L * 65536 * 4);       // [z][n][m] f32
    // aliases (lifetimes disjoint):
    ushort* P_ws = kbT;   // kbT dead after S-GEMM; spsm writes P, PV reads it
    ushort* obT  = qbT;   // qbT dead after S-GEMM; PV writes obT, final reads it
    (void)in_sizes; (void)n_in; (void)out_size; (void)ws_size;

    // 1) sparsity structure
    hipMemsetAsync(coo_cnt, 0, 4, stream);
    topk_kernel<<<256, 256, 0, stream>>>(coeff, coo_cnt, coo_m, coo_p, coo_v);
    csc_kernel<<<1, 256, 0, stream>>>(coo_cnt, coo_m, coo_p, coo_v, csc_ptr, csc_m, csc_v);

    // 2) weight converts + x transpose (f32 [b][512][256] -> bf16 [b][256][512])
    cvt4_kernel<<<dim3(1024, 4, 1), 256, 0, stream>>>(
        Wq, wqb, 2048 * 512, Wk, wkb, 2048 * 512, Wv, wvb, 2048 * 512, Wo, wob, 2048 * 2048);
    transpose_f32_bf16<<<dim3(8, 4, 32), 256, 0, stream>>>(x, xT, 512, 256);

    // 3) QKV projections (q,k written directly as [b][h][n][d]; v as [b][2048][256])
    gemm128<2, 1, 0><<<dim3(16, 2, 32), 256, 0, stream>>>(
        wqb, 0, xT, 256LL * 512, qbT, 0, bq, nullptr, 2048, 256, 512);
    gemm128<2, 1, 0><<<dim3(16, 2, 32), 256, 0, stream>>>(
        wkb, 0, xT, 256LL * 512, kbT, 0, bk, nullptr, 2048, 256, 512);
    gemm128<1, 1, 0><<<dim3(16, 2, 32), 256, 0, stream>>>(
        wvb, 0, xT, 256LL * 512, vb, 2048LL * 256, bv, nullptr, 2048, 256, 512);

    // 4) S = Q^T K / scale  -> f32 [z][n][m]
    gemm128<0, 0, 1><<<dim3(2, 2, 256), 256, 0, stream>>>(
        qbT, 65536, kbT, 65536, S_ws, 65536, nullptr, scale, 256, 256, 256);

    // 5) sparse combine + softmax -> P bf16 [z][n][p]
    spsm_kernel<<<256, 256, 0, stream>>>(S_ws, P_ws, csc_ptr, csc_m, csc_v);

    // 6) O[d][n] = sum_p V[d][p] P[n][p], written directly as obT [b][n][2048]
    gemm128<3, 0, 0><<<dim3(2, 2, 256), 256, 0, stream>>>(
        vb, 65536, P_ws, 65536, obT, 0, nullptr, nullptr, 256, 256, 256);

    // 7) final projection: out[b][i][n] = sum_o Wo[i][o] obT[b][n][o] + bo[i], f32 out
    gemm128<0, 1, 0><<<dim3(16, 2, 32), 256, 0, stream>>>(
        wob, 0, obT, 256LL * 2048, out, 2048LL * 256, bo, nullptr, 2048, 256, 2048);
}

// Round 5
// 494.469 us; speedup vs baseline: 1.1630x; 1.0231x over previous
//
#include <hip/hip_runtime.h>

typedef unsigned short ushort;
typedef __attribute__((ext_vector_type(8))) short short8;
typedef __attribute__((ext_vector_type(8))) unsigned short ushort8;
typedef __attribute__((ext_vector_type(4))) unsigned short ushort4v;
typedef __attribute__((ext_vector_type(4))) float fx4;

#define MAXNNZ (256*7)

__device__ __forceinline__ ushort f2bf(float f) {
    union { float f; unsigned u; } v; v.f = f;
    unsigned r = v.u + 0x7fffu + ((v.u >> 16) & 1u);
    return (ushort)(r >> 16);
}

__device__ __forceinline__ float bf2f(ushort b) {
    union { unsigned u; float f; } v; v.u = ((unsigned)b) << 16;
    return v.f;
}

// async global->LDS, 16B per lane; LDS dest = wave-uniform base + lane*16
__device__ __forceinline__ void gload_lds16(const ushort* g, ushort* l) {
    __builtin_amdgcn_global_load_lds(
        (const __attribute__((address_space(1))) unsigned int*)g,
        (__attribute__((address_space(3))) unsigned int*)l, 16, 0, 0);
}

// ---------------- top-7 per row of coeff (rows 0..255), emit COO for cols<256 -----
__global__ __launch_bounds__(256)
void topk_kernel(const float* __restrict__ coeff,
                 int* __restrict__ coo_cnt, int* __restrict__ coo_m,
                 int* __restrict__ coo_p, float* __restrict__ coo_v)
{
    int row = blockIdx.x;            // = m index, 0..255
    int tid = threadIdx.x;
    const float* crow = coeff + (long)row * 2048;
    float av[8];
#pragma unroll
    for (int i = 0; i < 8; ++i) av[i] = fabsf(crow[tid + 256 * i]);
    __shared__ unsigned long long red[256];
    for (int t = 0; t < 7; ++t) {
        float mx = -1.f; int mi = 0;
#pragma unroll
        for (int i = 0; i < 8; ++i) if (av[i] > mx) { mx = av[i]; mi = i; }
        unsigned col = (unsigned)(tid + 256 * mi);
        unsigned long long pk = ((unsigned long long)__float_as_uint(mx) << 32)
                              | (unsigned long long)(2048u - col); // tie -> smaller col
        red[tid] = pk; __syncthreads();
        for (int s = 128; s > 0; s >>= 1) {
            if (tid < s) { if (red[tid + s] > red[tid]) red[tid] = red[tid + s]; }
            __syncthreads();
        }
        unsigned long long w = red[0];
        __syncthreads();
        unsigned wcol = 2048u - (unsigned)(w & 0xffffffffu);
        if ((wcol & 255u) == (unsigned)tid) av[wcol >> 8] = -1.f; // consume
        if (tid == 0 && wcol < 256u) {
            int pos = atomicAdd(coo_cnt, 1);
            coo_m[pos] = row; coo_p[pos] = (int)wcol; coo_v[pos] = crow[wcol];
        }
    }
}

// ---------------- COO -> CSC (single block) ----------------
__global__ __launch_bounds__(256)
void csc_kernel(const int* __restrict__ coo_cnt, const int* __restrict__ coo_m,
                const int* __restrict__ coo_p, const float* __restrict__ coo_v,
                int* __restrict__ csc_ptr, int* __restrict__ csc_m, float* __restrict__ csc_v)
{
    __shared__ int cnt[256];
    __shared__ int off[257];
    __shared__ int cur[256];
    int tid = threadIdx.x;
    cnt[tid] = 0;
    __syncthreads();
    int n = *coo_cnt; if (n > MAXNNZ) n = MAXNNZ;
    for (int e = tid; e < n; e += 256) atomicAdd(&cnt[coo_p[e]], 1);
    __syncthreads();
    if (tid == 0) {
        int s = 0;
        for (int p = 0; p < 256; ++p) { off[p] = s; s += cnt[p]; }
        off[256] = s;
    }
    __syncthreads();
    csc_ptr[tid] = off[tid];
    if (tid == 0) csc_ptr[256] = off[256];
    cur[tid] = off[tid];
    __syncthreads();
    for (int e = tid; e < n; e += 256) {
        int p = coo_p[e];
        int pos = atomicAdd(&cur[p], 1);
        csc_m[pos] = coo_m[e];
        csc_v[pos] = coo_v[e];
    }
}

// ---------------- fp32 -> bf16 convert, 4 tensors in one launch ----------------
__global__ void cvt4_kernel(const float* a0, ushort* d0, int n0,
                            const float* a1, ushort* d1, int n1,
                            const float* a2, ushort* d2, int n2,
                            const float* a3, ushort* d3, int n3)
{
    const float* s; ushort* d; int n;
    switch (blockIdx.y) {
        case 0: s = a0; d = d0; n = n0; break;
        case 1: s = a1; d = d1; n = n1; break;
        case 2: s = a2; d = d2; n = n2; break;
        default: s = a3; d = d3; n = n3; break;
    }
    int nv = n >> 2;
    for (int i = blockIdx.x * blockDim.x + threadIdx.x; i < nv; i += gridDim.x * blockDim.x) {
        fx4 v = ((const fx4*)s)[i];
        ushort4v o;
        o[0] = f2bf(v[0]); o[1] = f2bf(v[1]); o[2] = f2bf(v[2]); o[3] = f2bf(v[3]);
        ((ushort4v*)d)[i] = o;
    }
}

// ---------------- transpose f32 [z][R][C] -> bf16 [z][C][R] ----------------
__global__ __launch_bounds__(256)
void transpose_f32_bf16(const float* __restrict__ in, ushort* __restrict__ out, int R, int C)
{
    int z = blockIdx.z;
    const float* ib = in + (long)z * R * C;
    ushort* ob = out + (long)z * R * C;
    __shared__ ushort tile[64][72];
    int r0 = blockIdx.x * 64, c0 = blockIdx.y * 64;
    int tid = threadIdx.x;
    int rl = tid >> 2, sg = tid & 3;
#pragma unroll
    for (int h = 0; h < 4; ++h) {
        fx4 v = *(const fx4*)(ib + (long)(r0 + rl) * C + c0 + h * 16 + sg * 4);
#pragma unroll
        for (int i = 0; i < 4; ++i) tile[h * 16 + sg * 4 + i][rl] = f2bf(v[i]);
    }
    __syncthreads();
    int cl = rl;
#pragma unroll
    for (int h = 0; h < 2; ++h) {
        ushort8 vv = *(const ushort8*)(&tile[cl][h * 32 + sg * 8]);
        *(ushort8*)(ob + (long)(c0 + cl) * R + r0 + h * 32 + sg * 8) = vv;
    }
}

// ---------------- K-combine: ktc[z][p][d] = sum_e csc_v[e] * kbT[z][m_e][d] --------
__global__ __launch_bounds__(256)
void kcomb_kernel(const ushort* __restrict__ kbT, ushort* __restrict__ ktc,
                  const int* __restrict__ csc_ptr, const int* __restrict__ csc_m,
                  const float* __restrict__ csc_v)
{
    int z = blockIdx.y;
    int tid = threadIdx.x;
    int p = blockIdx.x * 64 + (tid >> 2);
    int d0 = (tid & 3) * 64;
    const ushort* src = kbT + (long)z * 65536;
    float acc[64];
#pragma unroll
    for (int i = 0; i < 64; ++i) acc[i] = 0.f;
    int e0 = csc_ptr[p], e1 = csc_ptr[p + 1];
    for (int e = e0; e < e1; ++e) {
        const ushort* row = src + csc_m[e] * 256 + d0;
        float c = csc_v[e];
#pragma unroll
        for (int u = 0; u < 8; ++u) {
            ushort8 v = *(const ushort8*)(row + u * 8);
#pragma unroll
            for (int t = 0; t < 8; ++t) acc[u * 8 + t] += bf2f(v[t]) * c;
        }
    }
    ushort* dst = ktc + (long)z * 65536 + (long)p * 256 + d0;
#pragma unroll
    for (int u = 0; u < 8; ++u) {
        ushort8 o;
#pragma unroll
        for (int t = 0; t < 8; ++t) o[t] = f2bf(acc[u * 8 + t]);
        *(ushort8*)(dst + u * 8) = o;
    }
}

// ---------------- 128x128-tile NT GEMM: C[m][n2] = sum_k A[m][k]*B[n2][k] ----------
// MODE 3: PV batched (z grid): C bf16 obT, idx=(z>>3)*524288 + n2*2048 + (z&7)*256 + m
// MODE 4: merged QKV: N=8192 (z=n2>>8), A=[6144][512]; scatter to qbT/kbT/vb + bias
// MODE 5: merged final: N=8192 (z=n2>>8), f32 out + bias0[m]
template<int MODE>
__global__ __launch_bounds__(256)
void gemm128(const ushort* __restrict__ A, long long strideA,
             const ushort* __restrict__ B, long long strideB,
             void* __restrict__ C,
             const float* __restrict__ bias0, const float* __restrict__ bias1,
             const float* __restrict__ bias2,
             int N, int K)
{
    int z = blockIdx.z;
    const ushort* Ab = A + (long long)z * strideA;
    const ushort* Bb = B + (long long)z * strideB;
    int m0 = blockIdx.x * 128, n0 = blockIdx.y * 128;

    __shared__ __align__(16) ushort As[128 * 32];
    __shared__ __align__(16) ushort Bs[128 * 32];

    int tid = threadIdx.x;
    int wave = tid >> 6, lane = tid & 63;
    int wrow = wave >> 1, wcol = wave & 1;
    int l16 = lane & 15, quad = lane >> 4;
    int lrow = lane >> 2, lkq = lane & 3;

    fx4 acc[4][4];
#pragma unroll
    for (int i = 0; i < 4; ++i)
#pragma unroll
        for (int j = 0; j < 4; ++j) acc[i][j] = (fx4){0.f, 0.f, 0.f, 0.f};

    const ushort* gA0 = Ab + (long)(m0 + wave * 16 + lrow) * K + lkq * 8;
    const ushort* gA1 = gA0 + (long)64 * K;
    const ushort* gB0 = Bb + (long)(n0 + wave * 16 + lrow) * K + lkq * 8;
    const ushort* gB1 = gB0 + (long)64 * K;
    ushort* lA0 = As + (wave * 16) * 32;
    ushort* lA1 = As + (64 + wave * 16) * 32;
    ushort* lB0 = Bs + (wave * 16) * 32;
    ushort* lB1 = Bs + (64 + wave * 16) * 32;

    for (int kc = 0; kc < K; kc += 32) {
        __syncthreads();
        gload_lds16(gA0 + kc, lA0);
        gload_lds16(gA1 + kc, lA1);
        gload_lds16(gB0 + kc, lB0);
        gload_lds16(gB1 + kc, lB1);
        __syncthreads();

        short8 af[4], bf[4];
#pragma unroll
        for (int i = 0; i < 4; ++i)
            af[i] = *(const short8*)(As + (wrow * 64 + i * 16 + l16) * 32 + quad * 8);
#pragma unroll
        for (int j = 0; j < 4; ++j)
            bf[j] = *(const short8*)(Bs + (wcol * 64 + j * 16 + l16) * 32 + quad * 8);
#pragma unroll
        for (int i = 0; i < 4; ++i)
#pragma unroll
            for (int j = 0; j < 4; ++j)
                acc[i][j] = __builtin_amdgcn_mfma_f32_16x16x32_bf16(af[i], bf[j], acc[i][j], 0, 0, 0);
    }

#pragma unroll
    for (int i = 0; i < 4; ++i) {
#pragma unroll
        for (int j = 0; j < 4; ++j) {
#pragma unroll
            for (int r2 = 0; r2 < 4; ++r2) {
                int m = m0 + wrow * 64 + i * 16 + quad * 4 + r2;
                int n2 = n0 + wcol * 64 + j * 16 + l16;
                float v = acc[i][j][r2];
                if (MODE == 3) {
                    ((ushort*)C)[((long long)(z >> 3)) * 524288 + (long)n2 * 2048
                                 + (z & 7) * 256 + m] = f2bf(v);
                } else if (MODE == 4) {
                    int zb = n2 >> 8, n = n2 & 255;
                    int sec = m >> 11, ms = m & 2047;
                    v += (sec == 0 ? bias0[m] : (sec == 1 ? bias1[ms] : bias2[ms]));
                    long long idx;
                    if (sec < 2)  // q,k -> [sec][b][h][n][d]
                        idx = (long long)sec * 16777216 + (long long)zb * 524288
                            + (long)(ms >> 8) * 65536 + (long)n * 256 + (ms & 255);
                    else          // v -> [b][2048][256]
                        idx = 33554432LL + (long long)zb * 524288 + (long)ms * 256 + n;
                    ((ushort*)C)[idx] = f2bf(v);
                } else {          // MODE 5
                    int zb = n2 >> 8, n = n2 & 255;
                    v += bias0[m];
                    ((float*)C)[(long long)zb * 524288 + (long)m * 256 + n] = v;
                }
            }
        }
    }
}

// ---------------- T = (Q^T K~)/s with fused softmax -> P bf16 [z][n][p] ------------
// block: 128 n-rows x full 256 p-cols; waves 2x2 (wrow: n-half, wcol: p-half)
__global__ __launch_bounds__(256)
void tsm_kernel(const ushort* __restrict__ Q, const ushort* __restrict__ Kt,
                ushort* __restrict__ P, const float* __restrict__ scale_src)
{
    int z = blockIdx.y;
    const ushort* Ab = Q + (long)z * 65536;    // [n][d]
    const ushort* Bb = Kt + (long)z * 65536;   // [p][d]
    int n0 = blockIdx.x * 128;

    __shared__ __align__(16) ushort As[128 * 32];
    __shared__ __align__(16) ushort Bs[256 * 32];
    __shared__ float rmax[2][128];
    __shared__ float rsum[2][128];

    int tid = threadIdx.x;
    int wave = tid >> 6, lane = tid & 63;
    int wrow = wave >> 1, wcol = wave & 1;
    int l16 = lane & 15, quad = lane >> 4;
    int lrow = lane >> 2, lkq = lane & 3;

    fx4 acc[4][8];
#pragma unroll
    for (int i = 0; i < 4; ++i)
#pragma unroll
        for (int j = 0; j < 8; ++j) acc[i][j] = (fx4){0.f, 0.f, 0.f, 0.f};

    const ushort* gA0 = Ab + (long)(n0 + wave * 16 + lrow) * 256 + lkq * 8;
    const ushort* gA1 = gA0 + 64 * 256;
    const ushort* gB0 = Bb + (long)(wave * 16 + lrow) * 256 + lkq * 8;
    ushort* lA0 = As + (wave * 16) * 32;
    ushort* lA1 = As + (64 + wave * 16) * 32;
    ushort* lB0 = Bs + (wave * 16) * 32;

    for (int kc = 0; kc < 256; kc += 32) {
        __syncthreads();
        gload_lds16(gA0 + kc, lA0);
        gload_lds16(gA1 + kc, lA1);
        gload_lds16(gB0 + kc, lB0);
        gload_lds16(gB0 + 64 * 256 + kc, lB0 + 64 * 32);
        gload_lds16(gB0 + 128 * 256 + kc, lB0 + 128 * 32);
        gload_lds16(gB0 + 192 * 256 + kc, lB0 + 192 * 32);
        __syncthreads();

        short8 af[4], bf[8];
#pragma unroll
        for (int i = 0; i < 4; ++i)
            af[i] = *(const short8*)(As + (wrow * 64 + i * 16 + l16) * 32 + quad * 8);
#pragma unroll
        for (int j = 0; j < 8; ++j)
            bf[j] = *(const short8*)(Bs + (wcol * 128 + j * 16 + l16) * 32 + quad * 8);
#pragma unroll
        for (int i = 0; i < 4; ++i)
#pragma unroll
            for (int j = 0; j < 8; ++j)
                acc[i][j] = __builtin_amdgcn_mfma_f32_16x16x32_bf16(af[i], bf[j], acc[i][j], 0, 0, 0);
    }

    float sc = 1.0f / scale_src[0];
#pragma unroll
    for (int i = 0; i < 4; ++i)
#pragma unroll
        for (int j = 0; j < 8; ++j)
#pragma unroll
            for (int r = 0; r < 4; ++r) acc[i][j][r] *= sc;

    // --- row max: local over j, shfl over l16 (16-lane groups), LDS over wcol ---
    float lm[4][4];
#pragma unroll
    for (int i = 0; i < 4; ++i)
#pragma unroll
        for (int r = 0; r < 4; ++r) {
            float m = -1e30f;
#pragma unroll
            for (int j = 0; j < 8; ++j) m = fmaxf(m, acc[i][j][r]);
            lm[i][r] = m;
        }
#pragma unroll
    for (int d = 1; d < 16; d <<= 1)
#pragma unroll
        for (int i = 0; i < 4; ++i)
#pragma unroll
            for (int r = 0; r < 4; ++r) lm[i][r] = fmaxf(lm[i][r], __shfl_xor(lm[i][r], d, 16));
    if (l16 == 0) {
#pragma unroll
        for (int i = 0; i < 4; ++i)
#pragma unroll
            for (int r = 0; r < 4; ++r)
                rmax[wcol][wrow * 64 + i * 16 + quad * 4 + r] = lm[i][r];
    }
    __syncthreads();

    // --- exp + row sum ---
    float ls[4][4];
#pragma unroll
    for (int i = 0; i < 4; ++i)
#pragma unroll
        for (int r = 0; r < 4; ++r) {
            int row = wrow * 64 + i * 16 + quad * 4 + r;
            float M = fmaxf(rmax[0][row], rmax[1][row]);
            float s = 0.f;
#pragma unroll
            for (int j = 0; j < 8; ++j) {
                float e = __expf(acc[i][j][r] - M);
                acc[i][j][r] = e;
                s += e;
            }
            ls[i][r] = s;
        }
#pragma unroll
    for (int d = 1; d < 16; d <<= 1)
#pragma unroll
        for (int i = 0; i < 4; ++i)
#pragma unroll
            for (int r = 0; r < 4; ++r) ls[i][r] += __shfl_xor(ls[i][r], d, 16);
    if (l16 == 0) {
#pragma unroll
        for (int i = 0; i < 4; ++i)
#pragma unroll
            for (int r = 0; r < 4; ++r)
                rsum[wcol][wrow * 64 + i * 16 + quad * 4 + r] = ls[i][r];
    }
    __syncthreads();

    // --- normalize + write P ---
    ushort* Pb = P + (long)z * 65536;
#pragma unroll
    for (int i = 0; i < 4; ++i)
#pragma unroll
        for (int r = 0; r < 4; ++r) {
            int row = wrow * 64 + i * 16 + quad * 4 + r;
            float inv = 1.0f / (rsum[0][row] + rsum[1][row]);
#pragma unroll
            for (int j = 0; j < 8; ++j)
                Pb[(long)(n0 + row) * 256 + wcol * 128 + j * 16 + l16] = f2bf(acc[i][j][r] * inv);
        }
}

extern "C" void kernel_launch(void* const* d_in, const int* in_sizes, int n_in,
                              void* d_out, int out_size, void* d_ws, size_t ws_size,
                              hipStream_t stream)
{
    const float* x     = (const float*)d_in[0];
    const float* Wq    = (const float*)d_in[1];
    const float* bq    = (const float*)d_in[2];
    const float* Wk    = (const float*)d_in[3];
    const float* bk    = (const float*)d_in[4];
    const float* Wv    = (const float*)d_in[5];
    const float* bv    = (const float*)d_in[6];
    const float* Wo    = (const float*)d_in[7];
    const float* bo    = (const float*)d_in[8];
    const float* coeff = (const float*)d_in[9];
    const float* scale = (const float*)d_in[10];
    float* out = (float*)d_out;

    size_t o = 0;
    char* w = (char*)d_ws;
    auto take = [&](size_t bytes) -> void* {
        void* p = w + o; o += (bytes + 255) & ~(size_t)255; return p;
    };
    int*    coo_cnt = (int*)take(4);
    int*    coo_m   = (int*)take(MAXNNZ * 4);
    int*    coo_p   = (int*)take(MAXNNZ * 4);
    float*  coo_v   = (float*)take(MAXNNZ * 4);
    int*    csc_ptr = (int*)take(257 * 4);
    int*    csc_m   = (int*)take(MAXNNZ * 4);
    float*  csc_v   = (float*)take(MAXNNZ * 4);
    ushort* wqkv = (ushort*)take(6144L * 512 * 2);       // [wq;wk;wv] stacked
    ushort* wob  = (ushort*)take(2048L * 2048 * 2);
    ushort* xT   = (ushort*)take(32L * 256 * 512 * 2);   // [b][n][cin] == [8192][512]
    ushort* qkv  = (ushort*)take(3 * 16777216L * 2);     // qbT | kbT | vb contiguous
    ushort* qbT = qkv;                                   // [b][h][n][d]
    ushort* kbT = qkv + 16777216L;                       // [b][h][m][d]
    ushort* vb  = qkv + 33554432L;                       // [b][2048][256]
    ushort* ktc = (ushort*)take(16777216L * 2);          // [z][p][d]
    // aliases (lifetimes disjoint):
    ushort* P_ws = kbT;   // kbT dead after kcomb; tsm writes P, PV reads it
    ushort* obT  = qbT;   // qbT dead after tsm; PV writes obT == [8192][2048], final reads
    (void)in_sizes; (void)n_in; (void)out_size; (void)ws_size;

    // 1) sparsity structure
    hipMemsetAsync(coo_cnt, 0, 4, stream);
    topk_kernel<<<256, 256, 0, stream>>>(coeff, coo_cnt, coo_m, coo_p, coo_v);
    csc_kernel<<<1, 256, 0, stream>>>(coo_cnt, coo_m, coo_p, coo_v, csc_ptr, csc_m, csc_v);

    // 2) weight converts + x transpose
    cvt4_kernel<<<dim3(1024, 4, 1), 256, 0, stream>>>(
        Wq, wqkv, 2048 * 512, Wk, wqkv + 2048L * 512, 2048 * 512,
        Wv, wqkv + 4096L * 512, 2048 * 512, Wo, wob, 2048 * 2048);
    transpose_f32_bf16<<<dim3(8, 4, 32), 256, 0, stream>>>(x, xT, 512, 256);

    // 3) merged QKV projection: [6144,512] x [8192,512]^T, scatter epilogue
    gemm128<4><<<dim3(48, 64, 1), 256, 0, stream>>>(
        wqkv, 0, xT, 0, qkv, bq, bk, bv, 8192, 512);

    // 4) K-combine with sparse coeff: ktc[z][p][d]
    kcomb_kernel<<<dim3(4, 256), 256, 0, stream>>>(kbT, ktc, csc_ptr, csc_m, csc_v);

    // 5) T = (Q^T K~)/s, fused softmax -> P bf16 [z][n][p]
    tsm_kernel<<<dim3(2, 256), 256, 0, stream>>>(qbT, ktc, P_ws, scale);

    // 6) O[d][n] = sum_p V[d][p] P[n][p] -> obT [8192][2048]
    gemm128<3><<<dim3(2, 2, 256), 256, 0, stream>>>(
        vb, 65536, P_ws, 65536, obT, nullptr, nullptr, nullptr, 256, 256);

    // 7) merged final projection: [2048,2048] x [8192,2048]^T -> out f32 [b][2048][256]
    gemm128<5><<<dim3(16, 64, 1), 256, 0, stream>>>(
        wob, 0, obT, 0, out, bo, nullptr, nullptr, 8192, 2048);
}

// Round 6
// 431.708 us; speedup vs baseline: 1.3321x; 1.1454x over previous
//
#include <hip/hip_runtime.h>

typedef unsigned short ushort;
typedef __attribute__((ext_vector_type(8))) short short8;
typedef __attribute__((ext_vector_type(8))) unsigned short ushort8;
typedef __attribute__((ext_vector_type(4))) unsigned short ushort4v;
typedef __attribute__((ext_vector_type(4))) float fx4;

#define MAXNNZ (256*7)

__device__ __forceinline__ ushort f2bf(float f) {
    union { float f; unsigned u; } v; v.f = f;
    unsigned r = v.u + 0x7fffu + ((v.u >> 16) & 1u);
    return (ushort)(r >> 16);
}

__device__ __forceinline__ float bf2f(ushort b) {
    union { unsigned u; float f; } v; v.u = ((unsigned)b) << 16;
    return v.f;
}

// async global->LDS, 16B per lane; LDS dest = wave-uniform base + lane*16
__device__ __forceinline__ void gload_lds16(const ushort* g, ushort* l) {
    __builtin_amdgcn_global_load_lds(
        (const __attribute__((address_space(1))) unsigned int*)g,
        (__attribute__((address_space(3))) unsigned int*)l, 16, 0, 0);
}

// ---------------- top-7 per row of coeff (rows 0..255), emit COO for cols<256 -----
__global__ __launch_bounds__(256)
void topk_kernel(const float* __restrict__ coeff,
                 int* __restrict__ coo_cnt, int* __restrict__ coo_m,
                 int* __restrict__ coo_p, float* __restrict__ coo_v)
{
    int row = blockIdx.x;            // = m index, 0..255
    int tid = threadIdx.x;
    const float* crow = coeff + (long)row * 2048;
    float av[8];
#pragma unroll
    for (int i = 0; i < 8; ++i) av[i] = fabsf(crow[tid + 256 * i]);
    __shared__ unsigned long long red[256];
    for (int t = 0; t < 7; ++t) {
        float mx = -1.f; int mi = 0;
#pragma unroll
        for (int i = 0; i < 8; ++i) if (av[i] > mx) { mx = av[i]; mi = i; }
        unsigned col = (unsigned)(tid + 256 * mi);
        unsigned long long pk = ((unsigned long long)__float_as_uint(mx) << 32)
                              | (unsigned long long)(2048u - col); // tie -> smaller col
        red[tid] = pk; __syncthreads();
        for (int s = 128; s > 0; s >>= 1) {
            if (tid < s) { if (red[tid + s] > red[tid]) red[tid] = red[tid + s]; }
            __syncthreads();
        }
        unsigned long long w = red[0];
        __syncthreads();
        unsigned wcol = 2048u - (unsigned)(w & 0xffffffffu);
        if ((wcol & 255u) == (unsigned)tid) av[wcol >> 8] = -1.f; // consume
        if (tid == 0 && wcol < 256u) {
            int pos = atomicAdd(coo_cnt, 1);
            coo_m[pos] = row; coo_p[pos] = (int)wcol; coo_v[pos] = crow[wcol];
        }
    }
}

// ---------------- COO -> CSC (single block) ----------------
__global__ __launch_bounds__(256)
void csc_kernel(const int* __restrict__ coo_cnt, const int* __restrict__ coo_m,
                const int* __restrict__ coo_p, const float* __restrict__ coo_v,
                int* __restrict__ csc_ptr, int* __restrict__ csc_m, float* __restrict__ csc_v)
{
    __shared__ int cnt[256];
    __shared__ int off[257];
    __shared__ int cur[256];
    int tid = threadIdx.x;
    cnt[tid] = 0;
    __syncthreads();
    int n = *coo_cnt; if (n > MAXNNZ) n = MAXNNZ;
    for (int e = tid; e < n; e += 256) atomicAdd(&cnt[coo_p[e]], 1);
    __syncthreads();
    if (tid == 0) {
        int s = 0;
        for (int p = 0; p < 256; ++p) { off[p] = s; s += cnt[p]; }
        off[256] = s;
    }
    __syncthreads();
    csc_ptr[tid] = off[tid];
    if (tid == 0) csc_ptr[256] = off[256];
    cur[tid] = off[tid];
    __syncthreads();
    for (int e = tid; e < n; e += 256) {
        int p = coo_p[e];
        int pos = atomicAdd(&cur[p], 1);
        csc_m[pos] = coo_m[e];
        csc_v[pos] = coo_v[e];
    }
}

// ---------------- fp32 -> bf16 convert, 4 tensors in one launch ----------------
__global__ void cvt4_kernel(const float* a0, ushort* d0, int n0,
                            const float* a1, ushort* d1, int n1,
                            const float* a2, ushort* d2, int n2,
                            const float* a3, ushort* d3, int n3)
{
    const float* s; ushort* d; int n;
    switch (blockIdx.y) {
        case 0: s = a0; d = d0; n = n0; break;
        case 1: s = a1; d = d1; n = n1; break;
        case 2: s = a2; d = d2; n = n2; break;
        default: s = a3; d = d3; n = n3; break;
    }
    int nv = n >> 2;
    for (int i = blockIdx.x * blockDim.x + threadIdx.x; i < nv; i += gridDim.x * blockDim.x) {
        fx4 v = ((const fx4*)s)[i];
        ushort4v o;
        o[0] = f2bf(v[0]); o[1] = f2bf(v[1]); o[2] = f2bf(v[2]); o[3] = f2bf(v[3]);
        ((ushort4v*)d)[i] = o;
    }
}

// ---------------- transpose f32 [z][R][C] -> bf16 [z][C][R] ----------------
__global__ __launch_bounds__(256)
void transpose_f32_bf16(const float* __restrict__ in, ushort* __restrict__ out, int R, int C)
{
    int z = blockIdx.z;
    const float* ib = in + (long)z * R * C;
    ushort* ob = out + (long)z * R * C;
    __shared__ ushort tile[64][72];
    int r0 = blockIdx.x * 64, c0 = blockIdx.y * 64;
    int tid = threadIdx.x;
    int rl = tid >> 2, sg = tid & 3;
#pragma unroll
    for (int h = 0; h < 4; ++h) {
        fx4 v = *(const fx4*)(ib + (long)(r0 + rl) * C + c0 + h * 16 + sg * 4);
#pragma unroll
        for (int i = 0; i < 4; ++i) tile[h * 16 + sg * 4 + i][rl] = f2bf(v[i]);
    }
    __syncthreads();
    int cl = rl;
#pragma unroll
    for (int h = 0; h < 2; ++h) {
        ushort8 vv = *(const ushort8*)(&tile[cl][h * 32 + sg * 8]);
        *(ushort8*)(ob + (long)(c0 + cl) * R + r0 + h * 32 + sg * 8) = vv;
    }
}

// ---------------- K-combine: ktc[z][p][d] = sum_e csc_v[e] * kbT[z][m_e][d] --------
__global__ __launch_bounds__(256)
void kcomb_kernel(const ushort* __restrict__ kbT, ushort* __restrict__ ktc,
                  const int* __restrict__ csc_ptr, const int* __restrict__ csc_m,
                  const float* __restrict__ csc_v)
{
    int z = blockIdx.y;
    int tid = threadIdx.x;
    int p = blockIdx.x * 64 + (tid >> 2);
    int d0 = (tid & 3) * 64;
    const ushort* src = kbT + (long)z * 65536;
    float acc[64];
#pragma unroll
    for (int i = 0; i < 64; ++i) acc[i] = 0.f;
    int e0 = csc_ptr[p], e1 = csc_ptr[p + 1];
    for (int e = e0; e < e1; ++e) {
        const ushort* row = src + csc_m[e] * 256 + d0;
        float c = csc_v[e];
#pragma unroll
        for (int u = 0; u < 8; ++u) {
            ushort8 v = *(const ushort8*)(row + u * 8);
#pragma unroll
            for (int t = 0; t < 8; ++t) acc[u * 8 + t] += bf2f(v[t]) * c;
        }
    }
    ushort* dst = ktc + (long)z * 65536 + (long)p * 256 + d0;
#pragma unroll
    for (int u = 0; u < 8; ++u) {
        ushort8 o;
#pragma unroll
        for (int t = 0; t < 8; ++t) o[t] = f2bf(acc[u * 8 + t]);
        *(ushort8*)(dst + u * 8) = o;
    }
}

// ---------------- 128x128-tile NT GEMM: C[m][n2] = sum_k A[m][k]*B[n2][k] ----------
// MODE 3: PV batched (z grid): C bf16 obT, idx=(z>>3)*524288 + n2*2048 + (z&7)*256 + m
//         (LDS re-tile epilogue: contiguous-in-m 16B stores)
// MODE 4: merged QKV: N=8192 (zb=n2>>8), A=[6144][512]; sec = m0>>11 block-uniform.
//         q/k: [sec][b][h][n][d] contiguous-in-d; v: [b][2048][256] contiguous-in-n.
//         (LDS re-tile epilogue, orientation per section)
// MODE 5: merged final: f32 out + bias0[m] (direct stores, already line-coalesced)
template<int MODE>
__global__ __launch_bounds__(256)
void gemm128(const ushort* __restrict__ A, long long strideA,
             const ushort* __restrict__ B, long long strideB,
             void* __restrict__ C,
             const float* __restrict__ bias0, const float* __restrict__ bias1,
             const float* __restrict__ bias2,
             int N, int K)
{
    int z = blockIdx.z;
    const ushort* Ab = A + (long long)z * strideA;
    const ushort* Bb = B + (long long)z * strideB;
    int m0 = blockIdx.x * 128, n0 = blockIdx.y * 128;

    __shared__ __align__(16) ushort As[128 * 32];
    __shared__ __align__(16) ushort Bs[128 * 32];
    // re-tile buffer for coalesced epilogue (MODE 3/4 only); 128 rows x 136 stride
    __shared__ __align__(16) ushort Ct[(MODE == 3 || MODE == 4) ? 128 * 136 : 8];

    int tid = threadIdx.x;
    int wave = tid >> 6, lane = tid & 63;
    int wrow = wave >> 1, wcol = wave & 1;
    int l16 = lane & 15, quad = lane >> 4;
    int lrow = lane >> 2, lkq = lane & 3;

    fx4 acc[4][4];
#pragma unroll
    for (int i = 0; i < 4; ++i)
#pragma unroll
        for (int j = 0; j < 4; ++j) acc[i][j] = (fx4){0.f, 0.f, 0.f, 0.f};

    const ushort* gA0 = Ab + (long)(m0 + wave * 16 + lrow) * K + lkq * 8;
    const ushort* gA1 = gA0 + (long)64 * K;
    const ushort* gB0 = Bb + (long)(n0 + wave * 16 + lrow) * K + lkq * 8;
    const ushort* gB1 = gB0 + (long)64 * K;
    ushort* lA0 = As + (wave * 16) * 32;
    ushort* lA1 = As + (64 + wave * 16) * 32;
    ushort* lB0 = Bs + (wave * 16) * 32;
    ushort* lB1 = Bs + (64 + wave * 16) * 32;

    for (int kc = 0; kc < K; kc += 32) {
        __syncthreads();
        gload_lds16(gA0 + kc, lA0);
        gload_lds16(gA1 + kc, lA1);
        gload_lds16(gB0 + kc, lB0);
        gload_lds16(gB1 + kc, lB1);
        __syncthreads();

        short8 af[4], bf[4];
#pragma unroll
        for (int i = 0; i < 4; ++i)
            af[i] = *(const short8*)(As + (wrow * 64 + i * 16 + l16) * 32 + quad * 8);
#pragma unroll
        for (int j = 0; j < 4; ++j)
            bf[j] = *(const short8*)(Bs + (wcol * 64 + j * 16 + l16) * 32 + quad * 8);
#pragma unroll
        for (int i = 0; i < 4; ++i)
#pragma unroll
            for (int j = 0; j < 4; ++j)
                acc[i][j] = __builtin_amdgcn_mfma_f32_16x16x32_bf16(af[i], bf[j], acc[i][j], 0, 0, 0);
    }

    if (MODE == 5) {
        // direct f32 stores: lanes cover 16 consecutive n -> 64B lines
#pragma unroll
        for (int i = 0; i < 4; ++i)
#pragma unroll
            for (int j = 0; j < 4; ++j)
#pragma unroll
                for (int r2 = 0; r2 < 4; ++r2) {
                    int m = m0 + wrow * 64 + i * 16 + quad * 4 + r2;
                    int n2 = n0 + wcol * 64 + j * 16 + l16;
                    int zb = n2 >> 8, n = n2 & 255;
                    ((float*)C)[(long long)zb * 524288 + (long)m * 256 + n]
                        = acc[i][j][r2] + bias0[m];
                }
        return;
    }

    if (MODE == 3) {
        // orientation [n][m]: dest contiguous in m
#pragma unroll
        for (int i = 0; i < 4; ++i)
#pragma unroll
            for (int j = 0; j < 4; ++j) {
                int ml = wrow * 64 + i * 16 + quad * 4;
                int nl = wcol * 64 + j * 16 + l16;
                ushort4v pk;
#pragma unroll
                for (int r = 0; r < 4; ++r) pk[r] = f2bf(acc[i][j][r]);
                *(ushort4v*)(Ct + nl * 136 + ml) = pk;
            }
        __syncthreads();
        long long zb = z >> 3; int zh = z & 7;
        int nl = tid >> 3, mc = (tid & 7) * 16;
#pragma unroll
        for (int p4 = 0; p4 < 4; ++p4) {
            int n = p4 * 32 + nl;
            ushort8 v0 = *(const ushort8*)(Ct + n * 136 + mc);
            ushort8 v1 = *(const ushort8*)(Ct + n * 136 + mc + 8);
            ushort* dst = (ushort*)C + zb * 524288 + (long)(n0 + n) * 2048
                        + zh * 256 + m0 + mc;
            *(ushort8*)dst = v0;
            *(ushort8*)(dst + 8) = v1;
        }
        return;
    }

    if (MODE == 4) {
        int sec = m0 >> 11;            // block-uniform: 0=q, 1=k, 2=v
        int ms0 = m0 & 2047;
        int zb = n0 >> 8, nlo = n0 & 255;
        if (sec < 2) {
            const float* bs = (sec == 0) ? bias0 : bias1;
            // orientation [n][m]: dest contiguous in d(=m)
#pragma unroll
            for (int i = 0; i < 4; ++i)
#pragma unroll
                for (int j = 0; j < 4; ++j) {
                    int ml = wrow * 64 + i * 16 + quad * 4;
                    int nl = wcol * 64 + j * 16 + l16;
                    ushort4v pk;
#pragma unroll
                    for (int r = 0; r < 4; ++r)
                        pk[r] = f2bf(acc[i][j][r] + bs[ms0 + ml + r]);
                    *(ushort4v*)(Ct + nl * 136 + ml) = pk;
                }
            __syncthreads();
            int h = ms0 >> 8, d0 = m0 & 255;
            int nl = tid >> 3, mc = (tid & 7) * 16;
            ushort* base = (ushort*)C + (long long)sec * 16777216
                         + (long long)zb * 524288 + (long)h * 65536;
#pragma unroll
            for (int p4 = 0; p4 < 4; ++p4) {
                int n = p4 * 32 + nl;
                ushort8 v0 = *(const ushort8*)(Ct + n * 136 + mc);
                ushort8 v1 = *(const ushort8*)(Ct + n * 136 + mc + 8);
                ushort* dst = base + (long)(nlo + n) * 256 + d0 + mc;
                *(ushort8*)dst = v0;
                *(ushort8*)(dst + 8) = v1;
            }
        } else {
            // orientation [m][n]: dest contiguous in n
#pragma unroll
            for (int i = 0; i < 4; ++i)
#pragma unroll
                for (int j = 0; j < 4; ++j) {
                    int ml = wrow * 64 + i * 16 + quad * 4;
                    int nl = wcol * 64 + j * 16 + l16;
#pragma unroll
                    for (int r = 0; r < 4; ++r)
                        Ct[(ml + r) * 136 + nl] = f2bf(acc[i][j][r] + bias2[ms0 + ml + r]);
                }
            __syncthreads();
            int ml = tid >> 3, nc = (tid & 7) * 16;
            ushort* base = (ushort*)C + 33554432LL + (long long)zb * 524288;
#pragma unroll
            for (int p4 = 0; p4 < 4; ++p4) {
                int m = p4 * 32 + ml;
                ushort8 v0 = *(const ushort8*)(Ct + m * 136 + nc);
                ushort8 v1 = *(const ushort8*)(Ct + m * 136 + nc + 8);
                ushort* dst = base + (long)(ms0 + m) * 256 + nlo + nc;
                *(ushort8*)dst = v0;
                *(ushort8*)(dst + 8) = v1;
            }
        }
        return;
    }
}

// ---------------- T = (Q^T K~)/s with fused softmax -> P bf16 [z][n][p] ------------
// block: 128 n-rows x full 256 p-cols; waves 2x2 (wrow: n-half, wcol: p-half)
__global__ __launch_bounds__(256)
void tsm_kernel(const ushort* __restrict__ Q, const ushort* __restrict__ Kt,
                ushort* __restrict__ P, const float* __restrict__ scale_src)
{
    int z = blockIdx.y;
    const ushort* Ab = Q + (long)z * 65536;    // [n][d]
    const ushort* Bb = Kt + (long)z * 65536;   // [p][d]
    int n0 = blockIdx.x * 128;

    __shared__ __align__(16) ushort As[128 * 32];
    __shared__ __align__(16) ushort Bs[256 * 32];
    __shared__ float rmax[2][128];
    __shared__ float rsum[2][128];

    int tid = threadIdx.x;
    int wave = tid >> 6, lane = tid & 63;
    int wrow = wave >> 1, wcol = wave & 1;
    int l16 = lane & 15, quad = lane >> 4;
    int lrow = lane >> 2, lkq = lane & 3;

    fx4 acc[4][8];
#pragma unroll
    for (int i = 0; i < 4; ++i)
#pragma unroll
        for (int j = 0; j < 8; ++j) acc[i][j] = (fx4){0.f, 0.f, 0.f, 0.f};

    const ushort* gA0 = Ab + (long)(n0 + wave * 16 + lrow) * 256 + lkq * 8;
    const ushort* gA1 = gA0 + 64 * 256;
    const ushort* gB0 = Bb + (long)(wave * 16 + lrow) * 256 + lkq * 8;
    ushort* lA0 = As + (wave * 16) * 32;
    ushort* lA1 = As + (64 + wave * 16) * 32;
    ushort* lB0 = Bs + (wave * 16) * 32;

    for (int kc = 0; kc < 256; kc += 32) {
        __syncthreads();
        gload_lds16(gA0 + kc, lA0);
        gload_lds16(gA1 + kc, lA1);
        gload_lds16(gB0 + kc, lB0);
        gload_lds16(gB0 + 64 * 256 + kc, lB0 + 64 * 32);
        gload_lds16(gB0 + 128 * 256 + kc, lB0 + 128 * 32);
        gload_lds16(gB0 + 192 * 256 + kc, lB0 + 192 * 32);
        __syncthreads();

        short8 af[4], bf[8];
#pragma unroll
        for (int i = 0; i < 4; ++i)
            af[i] = *(const short8*)(As + (wrow * 64 + i * 16 + l16) * 32 + quad * 8);
#pragma unroll
        for (int j = 0; j < 8; ++j)
            bf[j] = *(const short8*)(Bs + (wcol * 128 + j * 16 + l16) * 32 + quad * 8);
#pragma unroll
        for (int i = 0; i < 4; ++i)
#pragma unroll
            for (int j = 0; j < 8; ++j)
                acc[i][j] = __builtin_amdgcn_mfma_f32_16x16x32_bf16(af[i], bf[j], acc[i][j], 0, 0, 0);
    }

    float sc = 1.0f / scale_src[0];
#pragma unroll
    for (int i = 0; i < 4; ++i)
#pragma unroll
        for (int j = 0; j < 8; ++j)
#pragma unroll
            for (int r = 0; r < 4; ++r) acc[i][j][r] *= sc;

    // --- row max: local over j, shfl over l16 (16-lane groups), LDS over wcol ---
    float lm[4][4];
#pragma unroll
    for (int i = 0; i < 4; ++i)
#pragma unroll
        for (int r = 0; r < 4; ++r) {
            float m = -1e30f;
#pragma unroll
            for (int j = 0; j < 8; ++j) m = fmaxf(m, acc[i][j][r]);
            lm[i][r] = m;
        }
#pragma unroll
    for (int d = 1; d < 16; d <<= 1)
#pragma unroll
        for (int i = 0; i < 4; ++i)
#pragma unroll
            for (int r = 0; r < 4; ++r) lm[i][r] = fmaxf(lm[i][r], __shfl_xor(lm[i][r], d, 16));
    if (l16 == 0) {
#pragma unroll
        for (int i = 0; i < 4; ++i)
#pragma unroll
            for (int r = 0; r < 4; ++r)
                rmax[wcol][wrow * 64 + i * 16 + quad * 4 + r] = lm[i][r];
    }
    __syncthreads();

    // --- exp + row sum ---
    float ls[4][4];
#pragma unroll
    for (int i = 0; i < 4; ++i)
#pragma unroll
        for (int r = 0; r < 4; ++r) {
            int row = wrow * 64 + i * 16 + quad * 4 + r;
            float M = fmaxf(rmax[0][row], rmax[1][row]);
            float s = 0.f;
#pragma unroll
            for (int j = 0; j < 8; ++j) {
                float e = __expf(acc[i][j][r] - M);
                acc[i][j][r] = e;
                s += e;
            }
            ls[i][r] = s;
        }
#pragma unroll
    for (int d = 1; d < 16; d <<= 1)
#pragma unroll
        for (int i = 0; i < 4; ++i)
#pragma unroll
            for (int r = 0; r < 4; ++r) ls[i][r] += __shfl_xor(ls[i][r], d, 16);
    if (l16 == 0) {
#pragma unroll
        for (int i = 0; i < 4; ++i)
#pragma unroll
            for (int r = 0; r < 4; ++r)
                rsum[wcol][wrow * 64 + i * 16 + quad * 4 + r] = ls[i][r];
    }
    __syncthreads();

    // --- normalize + write P ---
    ushort* Pb = P + (long)z * 65536;
#pragma unroll
    for (int i = 0; i < 4; ++i)
#pragma unroll
        for (int r = 0; r < 4; ++r) {
            int row = wrow * 64 + i * 16 + quad * 4 + r;
            float inv = 1.0f / (rsum[0][row] + rsum[1][row]);
#pragma unroll
            for (int j = 0; j < 8; ++j)
                Pb[(long)(n0 + row) * 256 + wcol * 128 + j * 16 + l16] = f2bf(acc[i][j][r] * inv);
        }
}

extern "C" void kernel_launch(void* const* d_in, const int* in_sizes, int n_in,
                              void* d_out, int out_size, void* d_ws, size_t ws_size,
                              hipStream_t stream)
{
    const float* x     = (const float*)d_in[0];
    const float* Wq    = (const float*)d_in[1];
    const float* bq    = (const float*)d_in[2];
    const float* Wk    = (const float*)d_in[3];
    const float* bk    = (const float*)d_in[4];
    const float* Wv    = (const float*)d_in[5];
    const float* bv    = (const float*)d_in[6];
    const float* Wo    = (const float*)d_in[7];
    const float* bo    = (const float*)d_in[8];
    const float* coeff = (const float*)d_in[9];
    const float* scale = (const float*)d_in[10];
    float* out = (float*)d_out;

    size_t o = 0;
    char* w = (char*)d_ws;
    auto take = [&](size_t bytes) -> void* {
        void* p = w + o; o += (bytes + 255) & ~(size_t)255; return p;
    };
    int*    coo_cnt = (int*)take(4);
    int*    coo_m   = (int*)take(MAXNNZ * 4);
    int*    coo_p   = (int*)take(MAXNNZ * 4);
    float*  coo_v   = (float*)take(MAXNNZ * 4);
    int*    csc_ptr = (int*)take(257 * 4);
    int*    csc_m   = (int*)take(MAXNNZ * 4);
    float*  csc_v   = (float*)take(MAXNNZ * 4);
    ushort* wqkv = (ushort*)take(6144L * 512 * 2);       // [wq;wk;wv] stacked
    ushort* wob  = (ushort*)take(2048L * 2048 * 2);
    ushort* xT   = (ushort*)take(32L * 256 * 512 * 2);   // [b][n][cin] == [8192][512]
    ushort* qkv  = (ushort*)take(3 * 16777216L * 2);     // qbT | kbT | vb contiguous
    ushort* qbT = qkv;                                   // [b][h][n][d]
    ushort* kbT = qkv + 16777216L;                       // [b][h][m][d]
    ushort* vb  = qkv + 33554432L;                       // [b][2048][256]
    ushort* ktc = (ushort*)take(16777216L * 2);          // [z][p][d]
    // aliases (lifetimes disjoint):
    ushort* P_ws = kbT;   // kbT dead after kcomb; tsm writes P, PV reads it
    ushort* obT  = qbT;   // qbT dead after tsm; PV writes obT == [8192][2048], final reads
    (void)in_sizes; (void)n_in; (void)out_size; (void)ws_size;

    // 1) sparsity structure
    hipMemsetAsync(coo_cnt, 0, 4, stream);
    topk_kernel<<<256, 256, 0, stream>>>(coeff, coo_cnt, coo_m, coo_p, coo_v);
    csc_kernel<<<1, 256, 0, stream>>>(coo_cnt, coo_m, coo_p, coo_v, csc_ptr, csc_m, csc_v);

    // 2) weight converts + x transpose
    cvt4_kernel<<<dim3(1024, 4, 1), 256, 0, stream>>>(
        Wq, wqkv, 2048 * 512, Wk, wqkv + 2048L * 512, 2048 * 512,
        Wv, wqkv + 4096L * 512, 2048 * 512, Wo, wob, 2048 * 2048);
    transpose_f32_bf16<<<dim3(8, 4, 32), 256, 0, stream>>>(x, xT, 512, 256);

    // 3) merged QKV projection: [6144,512] x [8192,512]^T, coalesced re-tile epilogue
    gemm128<4><<<dim3(48, 64, 1), 256, 0, stream>>>(
        wqkv, 0, xT, 0, qkv, bq, bk, bv, 8192, 512);

    // 4) K-combine with sparse coeff: ktc[z][p][d]
    kcomb_kernel<<<dim3(4, 256), 256, 0, stream>>>(kbT, ktc, csc_ptr, csc_m, csc_v);

    // 5) T = (Q^T K~)/s, fused softmax -> P bf16 [z][n][p]
    tsm_kernel<<<dim3(2, 256), 256, 0, stream>>>(qbT, ktc, P_ws, scale);

    // 6) O[d][n] = sum_p V[d][p] P[n][p] -> obT [8192][2048]
    gemm128<3><<<dim3(2, 2, 256), 256, 0, stream>>>(
        vb, 65536, P_ws, 65536, obT, nullptr, nullptr, nullptr, 256, 256);

    // 7) merged final projection: [2048,2048] x [8192,2048]^T -> out f32 [b][2048][256]
    gemm128<5><<<dim3(16, 64, 1), 256, 0, stream>>>(
        wob, 0, obT, 0, out, bo, nullptr, nullptr, 8192, 2048);
}